// Round 7
// baseline (519.608 us; speedup 1.0000x reference)
//
#include <hip/hip_runtime.h>
#include <hip/hip_bf16.h>

#define CL 2
#define CB 4
#define CT 1024
#define CD 256
#define CH 4
#define CM 1024
#define CHD (CH * CD)      // 1024
#define NROW (CB * CT)     // 4096

typedef unsigned short ushort_t;
typedef __attribute__((ext_vector_type(8))) short short8v;   // 8 bf16 (4 VGPR)
typedef __attribute__((ext_vector_type(4))) float float4v;   // MFMA C/D frag

#define LOG2E 1.44269504088896f

__device__ __forceinline__ float bf2f(unsigned short u) {
    return __uint_as_float(((unsigned int)u) << 16);
}
__device__ __forceinline__ unsigned short f2bf(float f) {
    unsigned int x = __float_as_uint(f);
    return (unsigned short)((x + 0x7fffu + ((x >> 16) & 1u)) >> 16);
}

// ---------------------------------------------------------------------------
// Input-dtype detection (2048 elems; fp32-underlying -> ~430 anomalies, bf16 0)
// ---------------------------------------------------------------------------
__global__ __launch_bounds__(256) void detect_kernel(
    const ushort_t* __restrict__ w, int n, int* __restrict__ flag)
{
    __shared__ int red[256];
    int c = 0;
    for (int i = threadIdx.x; i < n; i += 256) {
        float v = bf2f(w[i]);
        if (!(fabsf(v) <= 1e6f)) c++;
    }
    red[threadIdx.x] = c;
    __syncthreads();
    for (int s = 128; s > 0; s >>= 1) {
        if (threadIdx.x < s) red[threadIdx.x] += red[threadIdx.x + s];
        __syncthreads();
    }
    if (threadIdx.x == 0) flag[0] = (red[0] < 8) ? 1 : 0;
}

// ---------------------------------------------------------------------------
// Weight transpose+convert: in [Z][R][C] (+ioff elems, dtype per flag) ->
// out bf16 [Z][C][R].
// ---------------------------------------------------------------------------
__global__ __launch_bounds__(256) void tconv_kernel(
    const void* __restrict__ in, ushort_t* __restrict__ out,
    int R, int C, long inzs, long outzs, long ioff,
    const int* __restrict__ flagp)
{
    const int fbf = *flagp;
    __shared__ float tile[32][33];
    const long zi = ioff + (long)blockIdx.z * inzs;
    const long zo = (long)blockIdx.z * outzs;
    const int r0 = blockIdx.y * 32;
    const int c0 = blockIdx.x * 32;
    const int tx = threadIdx.x & 31;
    const int ty = threadIdx.x >> 5;
#pragma unroll
    for (int i = 0; i < 32; i += 8) {
        const long idx = zi + (long)(r0 + ty + i) * C + c0 + tx;
        tile[ty + i][tx] = fbf ? bf2f(((const ushort_t*)in)[idx])
                               : ((const float*)in)[idx];
    }
    __syncthreads();
#pragma unroll
    for (int i = 0; i < 32; i += 8)
        out[zo + (long)(c0 + ty + i) * R + r0 + tx] = f2bf(tile[tx][ty + i]);
}

// ---------------------------------------------------------------------------
// QKV projection (merged): A = xa [4096][256]; B = wqkvT[l] [3072][256]
// (rows: 0..1023 WqT, 1024..2047 WkT, 2048..3071 WvT). 128x128 tiles,
// grid (24,32) = 768 blocks (3/CU). Epilogue: cols<2048 -> qk row-major;
// cols>=2048 -> V transposed write into vT[bh][d][t].
// MFMA layout (verified r4-r6): D[m][n]=sum A[m][k]B[n][k];
// C/D row=quad*4+reg, col=lane&15.
// ---------------------------------------------------------------------------
__global__ __launch_bounds__(256) void qkv_proj(
    const ushort_t* __restrict__ A, const ushort_t* __restrict__ B,
    const void* __restrict__ bq, const void* __restrict__ bk,
    const void* __restrict__ bv, ushort_t* __restrict__ qk,
    ushort_t* __restrict__ vT, long boff, const int* __restrict__ flagp)
{
    const long m0 = (long)blockIdx.y * 128;
    const long n0 = (long)blockIdx.x * 128;

    __shared__ __align__(16) ushort_t As[128 * 32];
    __shared__ __align__(16) ushort_t Bs[128 * 32];

    const int tid = threadIdx.x;
    const int wave = tid >> 6;
    const int lane = tid & 63;
    const int quad = lane >> 4;
    const int lrow = lane & 15;
    const int wm = (wave >> 1) * 64;
    const int wn = (wave & 1) * 64;

    float4v acc[4][4];
#pragma unroll
    for (int i = 0; i < 4; ++i)
#pragma unroll
        for (int j = 0; j < 4; ++j)
            acc[i][j] = (float4v){0.f, 0.f, 0.f, 0.f};

    for (int k0 = 0; k0 < 256; k0 += 32) {
        __syncthreads();
#pragma unroll
        for (int p = 0; p < 2; ++p) {
            const int c = p * 256 + tid;
            const int row = c >> 2;
            const int kk = (c & 3) << 3;
            *reinterpret_cast<short8v*>(&As[c << 3]) =
                *reinterpret_cast<const short8v*>(&A[(m0 + row) * 256 + k0 + kk]);
            *reinterpret_cast<short8v*>(&Bs[c << 3]) =
                *reinterpret_cast<const short8v*>(&B[(n0 + row) * 256 + k0 + kk]);
        }
        __syncthreads();

        short8v af[4], bfv[4];
#pragma unroll
        for (int i = 0; i < 4; ++i) {
            af[i]  = *reinterpret_cast<const short8v*>(&As[(wm + i * 16 + lrow) * 32 + quad * 8]);
            bfv[i] = *reinterpret_cast<const short8v*>(&Bs[(wn + i * 16 + lrow) * 32 + quad * 8]);
        }
#pragma unroll
        for (int mi = 0; mi < 4; ++mi)
#pragma unroll
            for (int ni = 0; ni < 4; ++ni)
                acc[mi][ni] = __builtin_amdgcn_mfma_f32_16x16x32_bf16(
                    af[mi], bfv[ni], acc[mi][ni], 0, 0, 0);
    }

    const int fbf = *flagp;
#pragma unroll
    for (int mi = 0; mi < 4; ++mi) {
#pragma unroll
        for (int ni = 0; ni < 4; ++ni) {
            const long col = n0 + wn + ni * 16 + lrow;
            const long row0 = m0 + wm + mi * 16 + quad * 4;
            const void* bp;
            long bn;
            if (col < 1024)      { bp = bq; bn = col; }
            else if (col < 2048) { bp = bk; bn = col - 1024; }
            else                 { bp = bv; bn = col - 2048; }
            const float bias = fbf ? bf2f(((const ushort_t*)bp)[boff + bn])
                                   : ((const float*)bp)[boff + bn];
            if (col < 2048) {
#pragma unroll
                for (int r = 0; r < 4; ++r)
                    qk[(row0 + r) * 2048 + col] = f2bf(acc[mi][ni][r] + bias);
            } else {
                const long d = col - 2048;
                const long addr = ((row0 >> 10) << 2) * 262144 + d * 1024 + (row0 & 1023);
                ushort4 u;
                u.x = f2bf(acc[mi][ni][0] + bias);
                u.y = f2bf(acc[mi][ni][1] + bias);
                u.z = f2bf(acc[mi][ni][2] + bias);
                u.w = f2bf(acc[mi][ni][3] + bias);
                *reinterpret_cast<ushort4*>(&vT[addr]) = u;
            }
        }
    }
}

// ---------------------------------------------------------------------------
// mgemm64s: 64x64-tile split-K GEMM -> fp32 partials. Grid (N/64, M/64, 2).
// AMODE 0: plain bf16 A. AMODE 1: combined attention partials (op0/op1 +
// ml in log2-units -> exp2f combine during staging).
// ---------------------------------------------------------------------------
template <int AMODE>
__global__ __launch_bounds__(256) void mgemm64s(
    const ushort_t* __restrict__ A, const ushort_t* __restrict__ Ap1,
    const float2* __restrict__ ml, const ushort_t* __restrict__ B,
    float* __restrict__ P, int K2, int lda, int ldb)
{
    const int z = blockIdx.z;
    const long m0 = (long)blockIdx.y * 64;
    const long n0 = (long)blockIdx.x * 64;
    const int k_beg = z * K2;

    __shared__ __align__(16) ushort_t As[64 * 32];
    __shared__ __align__(16) ushort_t Bs[64 * 32];

    const int tid = threadIdx.x;
    const int wave = tid >> 6;
    const int lane = tid & 63;
    const int quad = lane >> 4;
    const int lrow = lane & 15;
    const int wm = (wave >> 1) * 32;
    const int wn = (wave & 1) * 32;

    const int ar = tid >> 2;
    const int ak = (tid & 3) << 3;

    float4v acc[2][2];
#pragma unroll
    for (int i = 0; i < 2; ++i)
#pragma unroll
        for (int j = 0; j < 2; ++j)
            acc[i][j] = (float4v){0.f, 0.f, 0.f, 0.f};

    for (int k0 = k_beg; k0 < k_beg + K2; k0 += 32) {
        __syncthreads();
        if constexpr (AMODE == 0) {
            *reinterpret_cast<short8v*>(&As[tid << 3]) =
                *reinterpret_cast<const short8v*>(&A[(m0 + ar) * (long)lda + k0 + ak]);
        } else {
            const long m = m0 + ar;
            const int hh = (k0 + ak) >> 8;
            const int bh = ((int)(m >> 10) << 2) + hh;
            const int trow = (int)(m & 1023);
            const float2 v0 = ml[bh * 1024 + trow];
            const float2 v1 = ml[(16 + bh) * 1024 + trow];
            const float mm = fmaxf(v0.x, v1.x);
            const float a0 = exp2f(v0.x - mm);
            const float a1 = exp2f(v1.x - mm);
            const float inv = 1.0f / (v0.y * a0 + v1.y * a1);
            const ushort4 u0a = *reinterpret_cast<const ushort4*>(&A[m * 1024 + k0 + ak]);
            const ushort4 u0b = *reinterpret_cast<const ushort4*>(&A[m * 1024 + k0 + ak + 4]);
            const ushort4 u1a = *reinterpret_cast<const ushort4*>(&Ap1[m * 1024 + k0 + ak]);
            const ushort4 u1b = *reinterpret_cast<const ushort4*>(&Ap1[m * 1024 + k0 + ak + 4]);
            short8v t8;
            t8[0] = (short)f2bf((bf2f(u0a.x) * a0 + bf2f(u1a.x) * a1) * inv);
            t8[1] = (short)f2bf((bf2f(u0a.y) * a0 + bf2f(u1a.y) * a1) * inv);
            t8[2] = (short)f2bf((bf2f(u0a.z) * a0 + bf2f(u1a.z) * a1) * inv);
            t8[3] = (short)f2bf((bf2f(u0a.w) * a0 + bf2f(u1a.w) * a1) * inv);
            t8[4] = (short)f2bf((bf2f(u0b.x) * a0 + bf2f(u1b.x) * a1) * inv);
            t8[5] = (short)f2bf((bf2f(u0b.y) * a0 + bf2f(u1b.y) * a1) * inv);
            t8[6] = (short)f2bf((bf2f(u0b.z) * a0 + bf2f(u1b.z) * a1) * inv);
            t8[7] = (short)f2bf((bf2f(u0b.w) * a0 + bf2f(u1b.w) * a1) * inv);
            *reinterpret_cast<short8v*>(&As[tid << 3]) = t8;
        }
        *reinterpret_cast<short8v*>(&Bs[tid << 3]) =
            *reinterpret_cast<const short8v*>(&B[(n0 + ar) * (long)ldb + k0 + ak]);
        __syncthreads();

        short8v af[2], bfv[2];
#pragma unroll
        for (int i = 0; i < 2; ++i) {
            af[i]  = *reinterpret_cast<const short8v*>(&As[(wm + i * 16 + lrow) * 32 + quad * 8]);
            bfv[i] = *reinterpret_cast<const short8v*>(&Bs[(wn + i * 16 + lrow) * 32 + quad * 8]);
        }
#pragma unroll
        for (int mi = 0; mi < 2; ++mi)
#pragma unroll
            for (int ni = 0; ni < 2; ++ni)
                acc[mi][ni] = __builtin_amdgcn_mfma_f32_16x16x32_bf16(
                    af[mi], bfv[ni], acc[mi][ni], 0, 0, 0);
    }

    float* Pz = P + (long)z * NROW * CD;
#pragma unroll
    for (int mi = 0; mi < 2; ++mi)
#pragma unroll
        for (int ni = 0; ni < 2; ++ni) {
            const long col = n0 + wn + ni * 16 + lrow;
            const long row0 = m0 + wm + mi * 16 + quad * 4;
#pragma unroll
            for (int r = 0; r < 4; ++r)
                Pz[(row0 + r) * CD + col] = acc[mi][ni][r];
        }
}

// ---------------------------------------------------------------------------
// mgemm64b: 64x64-tile full-K GEMM, bias(+relu), bf16 out. Grid (N/64, M/64).
// Used for MLP1: 1024 blocks = 4/CU (round-6 lesson: 256-block GEMMs are
// latency-bound at 1/CU).
// ---------------------------------------------------------------------------
template <int RELU>
__global__ __launch_bounds__(256) void mgemm64b(
    const ushort_t* __restrict__ A, const ushort_t* __restrict__ B,
    const void* __restrict__ bias, ushort_t* __restrict__ C,
    int K, int lda, int ldb, int ldc, long boff,
    const int* __restrict__ flagp)
{
    const long m0 = (long)blockIdx.y * 64;
    const long n0 = (long)blockIdx.x * 64;

    __shared__ __align__(16) ushort_t As[64 * 32];
    __shared__ __align__(16) ushort_t Bs[64 * 32];

    const int tid = threadIdx.x;
    const int wave = tid >> 6;
    const int lane = tid & 63;
    const int quad = lane >> 4;
    const int lrow = lane & 15;
    const int wm = (wave >> 1) * 32;
    const int wn = (wave & 1) * 32;

    const int ar = tid >> 2;
    const int ak = (tid & 3) << 3;

    float4v acc[2][2];
#pragma unroll
    for (int i = 0; i < 2; ++i)
#pragma unroll
        for (int j = 0; j < 2; ++j)
            acc[i][j] = (float4v){0.f, 0.f, 0.f, 0.f};

    for (int k0 = 0; k0 < K; k0 += 32) {
        __syncthreads();
        *reinterpret_cast<short8v*>(&As[tid << 3]) =
            *reinterpret_cast<const short8v*>(&A[(m0 + ar) * (long)lda + k0 + ak]);
        *reinterpret_cast<short8v*>(&Bs[tid << 3]) =
            *reinterpret_cast<const short8v*>(&B[(n0 + ar) * (long)ldb + k0 + ak]);
        __syncthreads();

        short8v af[2], bfv[2];
#pragma unroll
        for (int i = 0; i < 2; ++i) {
            af[i]  = *reinterpret_cast<const short8v*>(&As[(wm + i * 16 + lrow) * 32 + quad * 8]);
            bfv[i] = *reinterpret_cast<const short8v*>(&Bs[(wn + i * 16 + lrow) * 32 + quad * 8]);
        }
#pragma unroll
        for (int mi = 0; mi < 2; ++mi)
#pragma unroll
            for (int ni = 0; ni < 2; ++ni)
                acc[mi][ni] = __builtin_amdgcn_mfma_f32_16x16x32_bf16(
                    af[mi], bfv[ni], acc[mi][ni], 0, 0, 0);
    }

    const int fbf = *flagp;
#pragma unroll
    for (int mi = 0; mi < 2; ++mi)
#pragma unroll
        for (int ni = 0; ni < 2; ++ni) {
            const long col = n0 + wn + ni * 16 + lrow;
            const long row0 = m0 + wm + mi * 16 + quad * 4;
            const float bv = fbf ? bf2f(((const ushort_t*)bias)[boff + col])
                                 : ((const float*)bias)[boff + col];
#pragma unroll
            for (int r = 0; r < 4; ++r) {
                float v = acc[mi][ni][r] + bv;
                if (RELU) v = fmaxf(v, 0.f);
                C[(row0 + r) * (long)ldc + col] = f2bf(v);
            }
        }
}

// ---------------------------------------------------------------------------
// Flash attention, KV-split x2, 64-key tiles (round-6 lesson: 32-key tiles
// pay softmax/barrier per 32 keys -> 55% stall). LDS 79.9 KB -> 2 blocks/CU.
// exp2-domain softmax (scale*log2e folded). Writes UNNORMALIZED partial O
// and (m,l) in log2-units. qk is read-only.
// ---------------------------------------------------------------------------
__global__ __launch_bounds__(256) void flash_attn(
    const ushort_t* __restrict__ qk, const ushort_t* __restrict__ vT,
    ushort_t* __restrict__ op0, ushort_t* __restrict__ op1,
    float2* __restrict__ ml)
{
    const int bx = blockIdx.x;
    const int bh = bx & 15;
    const int qt = (bx >> 4) & 15;
    const int ck = bx >> 8;
    const int b = bh >> 2, h = bh & 3;

    __shared__ __align__(16) ushort_t Ks[64 * 264];     // 33792 B
    __shared__ __align__(16) ushort_t Vs[256 * 72];     // 36864 B
    __shared__ __align__(16) ushort_t Ps[4][16 * 72];   //  9216 B

    const int tid = threadIdx.x;
    const int wave = tid >> 6;
    const int lane = tid & 63;
    const int quad = lane >> 4;
    const int lrow = lane & 15;

    const long qrow0 = (long)b * CT + qt * 64;
    const int qcol = h * 256;
    const int kcol = 1024 + h * 256;
    const long vbase = (long)bh * 256 * 1024;
    const float SC = 0.0625f * LOG2E;

    short8v qf[8];
#pragma unroll
    for (int kk = 0; kk < 8; ++kk)
        qf[kk] = *reinterpret_cast<const short8v*>(
            &qk[(qrow0 + wave * 16 + lrow) * 2048 + qcol + kk * 32 + quad * 8]);

    float m4[4], l4[4];
#pragma unroll
    for (int r = 0; r < 4; ++r) { m4[r] = -1e30f; l4[r] = 0.f; }
    float4v oacc[16];
#pragma unroll
    for (int i = 0; i < 16; ++i) oacc[i] = (float4v){0.f, 0.f, 0.f, 0.f};

    const int t_beg = ck * 512;
    for (int t0 = t_beg; t0 < t_beg + 512; t0 += 64) {
        __syncthreads();
        // stage K 64x256 and V 256x64 (2048 16B-chunks each, 8/thread each)
#pragma unroll
        for (int p = 0; p < 8; ++p) {
            const int c = p * 256 + tid;
            {
                const int r = c >> 5, col = (c & 31) * 8;
                *reinterpret_cast<short8v*>(&Ks[r * 264 + col]) =
                    *reinterpret_cast<const short8v*>(
                        &qk[((long)b * CT + t0 + r) * 2048 + kcol + col]);
            }
            {
                const int r = c >> 3, col = (c & 7) * 8;
                *reinterpret_cast<short8v*>(&Vs[r * 72 + col]) =
                    *reinterpret_cast<const short8v*>(
                        &vT[vbase + (long)r * 1024 + t0 + col]);
            }
        }
        __syncthreads();

        // S strip: 16 q-rows x 64 keys, wave-private
        float4v sacc[4];
#pragma unroll
        for (int ni = 0; ni < 4; ++ni)
            sacc[ni] = (float4v){0.f, 0.f, 0.f, 0.f};
#pragma unroll
        for (int kk = 0; kk < 8; ++kk) {
#pragma unroll
            for (int ni = 0; ni < 4; ++ni) {
                short8v bk = *reinterpret_cast<const short8v*>(
                    &Ks[(ni * 16 + lrow) * 264 + kk * 32 + quad * 8]);
                sacc[ni] = __builtin_amdgcn_mfma_f32_16x16x32_bf16(
                    qf[kk], bk, sacc[ni], 0, 0, 0);
            }
        }
#pragma unroll
        for (int ni = 0; ni < 4; ++ni)
#pragma unroll
            for (int r = 0; r < 4; ++r)
                sacc[ni][r] *= SC;

        // online softmax (log2 domain): rows = quad*4+r, reduce over 16 lrow
        float alpha4[4];
#pragma unroll
        for (int r = 0; r < 4; ++r) {
            float mx = fmaxf(fmaxf(sacc[0][r], sacc[1][r]),
                             fmaxf(sacc[2][r], sacc[3][r]));
#pragma unroll
            for (int sh = 1; sh < 16; sh <<= 1)
                mx = fmaxf(mx, __shfl_xor(mx, sh));
            const float mnew = fmaxf(m4[r], mx);
            alpha4[r] = exp2f(m4[r] - mnew);
            m4[r] = mnew;
        }
#pragma unroll
        for (int ni = 0; ni < 4; ++ni)
#pragma unroll
            for (int r = 0; r < 4; ++r) {
                const float pv = exp2f(sacc[ni][r] - m4[r]);
                sacc[ni][r] = pv;
                Ps[wave][(quad * 4 + r) * 72 + ni * 16 + lrow] = f2bf(pv);
            }
#pragma unroll
        for (int r = 0; r < 4; ++r) {
            float s = (sacc[0][r] + sacc[1][r]) + (sacc[2][r] + sacc[3][r]);
#pragma unroll
            for (int sh = 1; sh < 16; sh <<= 1)
                s += __shfl_xor(s, sh);
            l4[r] = l4[r] * alpha4[r] + s;
        }
#pragma unroll
        for (int ni = 0; ni < 16; ++ni)
#pragma unroll
            for (int r = 0; r < 4; ++r)
                oacc[ni][r] *= alpha4[r];

        // O += P(16x64) @ V(64x256), two 32-key k-steps
#pragma unroll
        for (int s = 0; s < 2; ++s) {
            short8v ap = *reinterpret_cast<const short8v*>(
                &Ps[wave][lrow * 72 + s * 32 + quad * 8]);
#pragma unroll
            for (int ni = 0; ni < 16; ++ni) {
                short8v bv = *reinterpret_cast<const short8v*>(
                    &Vs[(ni * 16 + lrow) * 72 + s * 32 + quad * 8]);
                oacc[ni] = __builtin_amdgcn_mfma_f32_16x16x32_bf16(
                    ap, bv, oacc[ni], 0, 0, 0);
            }
        }
    }

    // epilogue: unnormalized partial O + (m,l) (log2-units)
#pragma unroll
    for (int r = 0; r < 4; ++r)
        if (lrow == 0)
            ml[((ck << 4) + bh) * 1024 + qt * 64 + wave * 16 + quad * 4 + r] =
                make_float2(m4[r], l4[r]);

    ushort_t* op = ck ? op1 : op0;
#pragma unroll
    for (int ni = 0; ni < 16; ++ni)
#pragma unroll
        for (int r = 0; r < 4; ++r)
            op[(qrow0 + wave * 16 + quad * 4 + r) * 1024 + (h << 8) + ni * 16 + lrow]
                = f2bf(oacc[ni][r]);
}

// ---------------------------------------------------------------------------
// ln_p: x = P0[row]+P1[row] + gbias + res; out = LN(x)*s + b (bf16).
// ---------------------------------------------------------------------------
__global__ __launch_bounds__(256) void ln_p(
    const float* __restrict__ p, const void* __restrict__ gb, long gboff,
    const ushort_t* __restrict__ res, const void* __restrict__ sc,
    const void* __restrict__ bi, ushort_t* __restrict__ out, long loff,
    const int* __restrict__ flagp)
{
    const int fbf = *flagp;
    const long row = (long)blockIdx.x * CD;
    const int t = threadIdx.x;
    const float gbv = fbf ? bf2f(((const ushort_t*)gb)[gboff + t])
                          : ((const float*)gb)[gboff + t];
    const float x = p[row + t] + p[(long)NROW * CD + row + t] + gbv + bf2f(res[row + t]);

    __shared__ float r1[256];
    __shared__ float r2[256];
    r1[t] = x;
    r2[t] = x * x;
    __syncthreads();
    for (int s = 128; s > 0; s >>= 1) {
        if (t < s) { r1[t] += r1[t + s]; r2[t] += r2[t + s]; }
        __syncthreads();
    }
    const float mean = r1[0] * (1.0f / CD);
    const float var = r2[0] * (1.0f / CD) - mean * mean;
    const float rstd = rsqrtf(var + 1e-5f);
    const float s_v = fbf ? bf2f(((const ushort_t*)sc)[loff + t]) : ((const float*)sc)[loff + t];
    const float b_v = fbf ? bf2f(((const ushort_t*)bi)[loff + t]) : ((const float*)bi)[loff + t];
    out[row + t] = f2bf((x - mean) * rstd * s_v + b_v);
}

__global__ __launch_bounds__(256) void in_convert(
    const void* __restrict__ in, ushort_t* __restrict__ x,
    const int* __restrict__ flagp)
{
    const int fbf = *flagp;
    const long i = ((long)blockIdx.x * 256 + threadIdx.x) << 2;
    if (fbf) {
        *reinterpret_cast<ushort4*>(x + i) =
            *reinterpret_cast<const ushort4*>((const ushort_t*)in + i);
    } else {
        float4 f = *reinterpret_cast<const float4*>((const float*)in + i);
        ushort4 u;
        u.x = f2bf(f.x); u.y = f2bf(f.y); u.z = f2bf(f.z); u.w = f2bf(f.w);
        *reinterpret_cast<ushort4*>(x + i) = u;
    }
}

__global__ __launch_bounds__(256) void out_write(
    const ushort_t* __restrict__ x, void* __restrict__ out,
    const int* __restrict__ flagp)
{
    const int fbf = *flagp;
    const long i = ((long)blockIdx.x * 256 + threadIdx.x) << 2;
    ushort4 u = *reinterpret_cast<const ushort4*>(x + i);
    if (fbf) {
        *reinterpret_cast<ushort4*>((ushort_t*)out + i) = u;
    } else {
        float4 f = make_float4(bf2f(u.x), bf2f(u.y), bf2f(u.z), bf2f(u.w));
        *reinterpret_cast<float4*>((float*)out + i) = f;
    }
}

// ---------------------------------------------------------------------------
// Orchestration. ws = 47.0 MB (< 48 known-safe).
// ---------------------------------------------------------------------------
extern "C" void kernel_launch(void* const* d_in, const int* in_sizes, int n_in,
                              void* d_out, int out_size, void* d_ws, size_t ws_size,
                              hipStream_t stream)
{
    const void* queries = d_in[0];
    const void* Wq = d_in[1];  const void* bq = d_in[2];
    const void* Wk = d_in[3];  const void* bk = d_in[4];
    const void* Wv = d_in[5];  const void* bv = d_in[6];
    const void* Wo = d_in[7];  const void* bo = d_in[8];
    const void* ln1s = d_in[9];  const void* ln1b = d_in[10];
    const void* W1 = d_in[11]; const void* b1 = d_in[12];
    const void* W2 = d_in[13]; const void* b2 = d_in[14];
    const void* ln2s = d_in[15]; const void* ln2b = d_in[16];

    char* p = (char*)d_ws;
    int* flagp = (int*)p;             p += 256;
    ushort_t* wqkvT = (ushort_t*)p;   p += (long)CL * 3072 * 256 * 2;  // 3 MB
    ushort_t* w1T   = (ushort_t*)p;   p += (long)CL * 1024 * 256 * 2;  // 1 MB
    ushort_t* wscr  = (ushort_t*)p;   p += (long)256 * 1024 * 2;       // 0.5 MB
    ushort_t* xa    = (ushort_t*)p;   p += (long)NROW * CD * 2;        // 2 MB
    ushort_t* qk    = (ushort_t*)p;   p += (long)NROW * 2048 * 2;      // 16 MB
    ushort_t* vT    = (ushort_t*)p;   p += (long)16 * 256 * 1024 * 2;  // 8 MB
    ushort_t* op0   = (ushort_t*)p;   p += (long)NROW * 1024 * 2;      // 8 MB
    ushort_t* op1   = (ushort_t*)p;   p += (long)NROW * 1024 * 2;      // 8 MB
    float2*   ml    = (float2*)p;     p += (long)2 * 16 * 1024 * 8;    // 0.25 MB
    ushort_t* h     = vT;             // MLP hidden reuses vT
    float*    pgem  = (float*)qk;     // fp32 partials reuse qk (dead post-flash)

    detect_kernel<<<1, 256, 0, stream>>>((const ushort_t*)Wq, 2048, flagp);

    // wqkvT[l] = [3072][256]: rows 0..1023 WqT | 1024..2047 WkT | 2048.. WvT
    tconv_kernel<<<dim3(32, 8, CL), 256, 0, stream>>>(
        Wq, wqkvT, 256, 1024, 256 * 1024, 3072 * 256, 0, flagp);
    tconv_kernel<<<dim3(32, 8, CL), 256, 0, stream>>>(
        Wk, wqkvT + 1024 * 256, 256, 1024, 256 * 1024, 3072 * 256, 0, flagp);
    tconv_kernel<<<dim3(32, 8, CL), 256, 0, stream>>>(
        Wv, wqkvT + 2048 * 256, 256, 1024, 256 * 1024, 3072 * 256, 0, flagp);
    tconv_kernel<<<dim3(32, 8, CL), 256, 0, stream>>>(
        W1, w1T, 256, 1024, 256 * 1024, 1024 * 256, 0, flagp);

    in_convert<<<(NROW * CD) / 1024, 256, 0, stream>>>(queries, xa, flagp);

    for (int l = 0; l < CL; ++l) {
        // 1) merged QKV projection -> qk [4096,2048] + vT[bh][d][t]
        qkv_proj<<<dim3(24, 32, 1), 256, 0, stream>>>(
            xa, wqkvT + (long)l * 3072 * 256, bq, bk, bv, qk, vT,
            (long)l * 1024, flagp);
        // 2) Wo^T -> wscr
        tconv_kernel<<<dim3(8, 32, 1), 256, 0, stream>>>(
            Wo, wscr, 1024, 256, 0, 0, (long)l * 1024 * 256, flagp);
        // 3) flash attention (512 blocks, 64-key tiles, KV-split x2)
        flash_attn<<<512, 256, 0, stream>>>(qk, vT, op0, op1, ml);
        // 4) O projection with fused partial-combine -> fp32 pgem
        mgemm64s<1><<<dim3(4, 64, 2), 256, 0, stream>>>(
            op0, op1, ml, wscr, pgem, 512, 1024, 1024);
        // 5) xa = LN(pgem0+pgem1 + bo + xa)
        ln_p<<<NROW, 256, 0, stream>>>(pgem, bo, (long)l * 256, xa,
                                       ln1s, ln1b, xa, (long)l * 256, flagp);
        // 6) h = relu(xa @ w1T^T + b1)  (1024 blocks = 4/CU)
        mgemm64b<1><<<dim3(16, 64, 1), 256, 0, stream>>>(
            xa, w1T + (long)l * 1024 * 256, b1, h,
            256, 256, 256, 1024, (long)l * 1024, flagp);
        // 7) W2^T -> wscr
        tconv_kernel<<<dim3(8, 32, 1), 256, 0, stream>>>(
            W2, wscr, 1024, 256, 0, 0, (long)l * 1024 * 256, flagp);
        // 8) MLP2 -> fp32 pgem
        mgemm64s<0><<<dim3(4, 64, 2), 256, 0, stream>>>(
            h, nullptr, nullptr, wscr, pgem, 512, 1024, 1024);
        // 9) xa = LN(pgem0+pgem1 + b2 + xa)
        ln_p<<<NROW, 256, 0, stream>>>(pgem, b2, (long)l * 256, xa,
                                       ln2s, ln2b, xa, (long)l * 256, flagp);
    }

    out_write<<<(NROW * CD) / 1024, 256, 0, stream>>>(xa, d_out, flagp);
}

// Round 8
// 456.304 us; speedup vs baseline: 1.1387x; 1.1387x over previous
//
#include <hip/hip_runtime.h>
#include <hip/hip_bf16.h>

#define CL 2
#define CB 4
#define CT 1024
#define CD 256
#define CH 4
#define CM 1024
#define CHD (CH * CD)      // 1024
#define NROW (CB * CT)     // 4096

typedef unsigned short ushort_t;
typedef __attribute__((ext_vector_type(8))) short short8v;   // 8 bf16 (4 VGPR)
typedef __attribute__((ext_vector_type(4))) float float4v;   // MFMA C/D frag

#define LOG2E 1.44269504088896f

__device__ __forceinline__ float bf2f(unsigned short u) {
    return __uint_as_float(((unsigned int)u) << 16);
}
__device__ __forceinline__ unsigned short f2bf(float f) {
    unsigned int x = __float_as_uint(f);
    return (unsigned short)((x + 0x7fffu + ((x >> 16) & 1u)) >> 16);
}

// ---------------------------------------------------------------------------
// Input-dtype detection (2048 elems; fp32-underlying -> ~430 anomalies, bf16 0)
// ---------------------------------------------------------------------------
__global__ __launch_bounds__(256) void detect_kernel(
    const ushort_t* __restrict__ w, int n, int* __restrict__ flag)
{
    __shared__ int red[256];
    int c = 0;
    for (int i = threadIdx.x; i < n; i += 256) {
        float v = bf2f(w[i]);
        if (!(fabsf(v) <= 1e6f)) c++;
    }
    red[threadIdx.x] = c;
    __syncthreads();
    for (int s = 128; s > 0; s >>= 1) {
        if (threadIdx.x < s) red[threadIdx.x] += red[threadIdx.x + s];
        __syncthreads();
    }
    if (threadIdx.x == 0) flag[0] = (red[0] < 8) ? 1 : 0;
}

// ---------------------------------------------------------------------------
// Weight transpose+convert: in [Z][R][C] (+ioff elems, dtype per flag) ->
// out bf16 [Z][C][R].
// ---------------------------------------------------------------------------
__global__ __launch_bounds__(256) void tconv_kernel(
    const void* __restrict__ in, ushort_t* __restrict__ out,
    int R, int C, long inzs, long outzs, long ioff,
    const int* __restrict__ flagp)
{
    const int fbf = *flagp;
    __shared__ float tile[32][33];
    const long zi = ioff + (long)blockIdx.z * inzs;
    const long zo = (long)blockIdx.z * outzs;
    const int r0 = blockIdx.y * 32;
    const int c0 = blockIdx.x * 32;
    const int tx = threadIdx.x & 31;
    const int ty = threadIdx.x >> 5;
#pragma unroll
    for (int i = 0; i < 32; i += 8) {
        const long idx = zi + (long)(r0 + ty + i) * C + c0 + tx;
        tile[ty + i][tx] = fbf ? bf2f(((const ushort_t*)in)[idx])
                               : ((const float*)in)[idx];
    }
    __syncthreads();
#pragma unroll
    for (int i = 0; i < 32; i += 8)
        out[zo + (long)(c0 + ty + i) * R + r0 + tx] = f2bf(tile[tx][ty + i]);
}

// ---------------------------------------------------------------------------
// QKV projection (merged, verified r7): A = xa [4096][256];
// B = wqkvT[l] [3072][256]. 128x128 tiles, grid (24,32)=768 blocks.
// cols<2048 -> qk row-major; cols>=2048 -> V transposed into vT[bh][d][t].
// ---------------------------------------------------------------------------
__global__ __launch_bounds__(256) void qkv_proj(
    const ushort_t* __restrict__ A, const ushort_t* __restrict__ B,
    const void* __restrict__ bq, const void* __restrict__ bk,
    const void* __restrict__ bv, ushort_t* __restrict__ qk,
    ushort_t* __restrict__ vT, long boff, const int* __restrict__ flagp)
{
    const long m0 = (long)blockIdx.y * 128;
    const long n0 = (long)blockIdx.x * 128;

    __shared__ __align__(16) ushort_t As[128 * 32];
    __shared__ __align__(16) ushort_t Bs[128 * 32];

    const int tid = threadIdx.x;
    const int wave = tid >> 6;
    const int lane = tid & 63;
    const int quad = lane >> 4;
    const int lrow = lane & 15;
    const int wm = (wave >> 1) * 64;
    const int wn = (wave & 1) * 64;

    float4v acc[4][4];
#pragma unroll
    for (int i = 0; i < 4; ++i)
#pragma unroll
        for (int j = 0; j < 4; ++j)
            acc[i][j] = (float4v){0.f, 0.f, 0.f, 0.f};

    for (int k0 = 0; k0 < 256; k0 += 32) {
        __syncthreads();
#pragma unroll
        for (int p = 0; p < 2; ++p) {
            const int c = p * 256 + tid;
            const int row = c >> 2;
            const int kk = (c & 3) << 3;
            *reinterpret_cast<short8v*>(&As[c << 3]) =
                *reinterpret_cast<const short8v*>(&A[(m0 + row) * 256 + k0 + kk]);
            *reinterpret_cast<short8v*>(&Bs[c << 3]) =
                *reinterpret_cast<const short8v*>(&B[(n0 + row) * 256 + k0 + kk]);
        }
        __syncthreads();

        short8v af[4], bfv[4];
#pragma unroll
        for (int i = 0; i < 4; ++i) {
            af[i]  = *reinterpret_cast<const short8v*>(&As[(wm + i * 16 + lrow) * 32 + quad * 8]);
            bfv[i] = *reinterpret_cast<const short8v*>(&Bs[(wn + i * 16 + lrow) * 32 + quad * 8]);
        }
#pragma unroll
        for (int mi = 0; mi < 4; ++mi)
#pragma unroll
            for (int ni = 0; ni < 4; ++ni)
                acc[mi][ni] = __builtin_amdgcn_mfma_f32_16x16x32_bf16(
                    af[mi], bfv[ni], acc[mi][ni], 0, 0, 0);
    }

    const int fbf = *flagp;
#pragma unroll
    for (int mi = 0; mi < 4; ++mi) {
#pragma unroll
        for (int ni = 0; ni < 4; ++ni) {
            const long col = n0 + wn + ni * 16 + lrow;
            const long row0 = m0 + wm + mi * 16 + quad * 4;
            const void* bp;
            long bn;
            if (col < 1024)      { bp = bq; bn = col; }
            else if (col < 2048) { bp = bk; bn = col - 1024; }
            else                 { bp = bv; bn = col - 2048; }
            const float bias = fbf ? bf2f(((const ushort_t*)bp)[boff + bn])
                                   : ((const float*)bp)[boff + bn];
            if (col < 2048) {
#pragma unroll
                for (int r = 0; r < 4; ++r)
                    qk[(row0 + r) * 2048 + col] = f2bf(acc[mi][ni][r] + bias);
            } else {
                const long d = col - 2048;
                const long addr = ((row0 >> 10) << 2) * 262144 + d * 1024 + (row0 & 1023);
                ushort4 u;
                u.x = f2bf(acc[mi][ni][0] + bias);
                u.y = f2bf(acc[mi][ni][1] + bias);
                u.z = f2bf(acc[mi][ni][2] + bias);
                u.w = f2bf(acc[mi][ni][3] + bias);
                *reinterpret_cast<ushort4*>(&vT[addr]) = u;
            }
        }
    }
}

// ---------------------------------------------------------------------------
// mgemm64s: 64x64-tile split-K GEMM -> fp32 partials. Grid (N/64, M/64, 2).
// AMODE 0: plain bf16 A. AMODE 1: combined attention partials (exp2 domain).
// ---------------------------------------------------------------------------
template <int AMODE>
__global__ __launch_bounds__(256) void mgemm64s(
    const ushort_t* __restrict__ A, const ushort_t* __restrict__ Ap1,
    const float2* __restrict__ ml, const ushort_t* __restrict__ B,
    float* __restrict__ P, int K2, int lda, int ldb)
{
    const int z = blockIdx.z;
    const long m0 = (long)blockIdx.y * 64;
    const long n0 = (long)blockIdx.x * 64;
    const int k_beg = z * K2;

    __shared__ __align__(16) ushort_t As[64 * 32];
    __shared__ __align__(16) ushort_t Bs[64 * 32];

    const int tid = threadIdx.x;
    const int wave = tid >> 6;
    const int lane = tid & 63;
    const int quad = lane >> 4;
    const int lrow = lane & 15;
    const int wm = (wave >> 1) * 32;
    const int wn = (wave & 1) * 32;

    const int ar = tid >> 2;
    const int ak = (tid & 3) << 3;

    float4v acc[2][2];
#pragma unroll
    for (int i = 0; i < 2; ++i)
#pragma unroll
        for (int j = 0; j < 2; ++j)
            acc[i][j] = (float4v){0.f, 0.f, 0.f, 0.f};

    for (int k0 = k_beg; k0 < k_beg + K2; k0 += 32) {
        __syncthreads();
        if constexpr (AMODE == 0) {
            *reinterpret_cast<short8v*>(&As[tid << 3]) =
                *reinterpret_cast<const short8v*>(&A[(m0 + ar) * (long)lda + k0 + ak]);
        } else {
            const long m = m0 + ar;
            const int hh = (k0 + ak) >> 8;
            const int bh = ((int)(m >> 10) << 2) + hh;
            const int trow = (int)(m & 1023);
            const float2 v0 = ml[bh * 1024 + trow];
            const float2 v1 = ml[(16 + bh) * 1024 + trow];
            const float mm = fmaxf(v0.x, v1.x);
            const float a0 = exp2f(v0.x - mm);
            const float a1 = exp2f(v1.x - mm);
            const float inv = 1.0f / (v0.y * a0 + v1.y * a1);
            const ushort4 u0a = *reinterpret_cast<const ushort4*>(&A[m * 1024 + k0 + ak]);
            const ushort4 u0b = *reinterpret_cast<const ushort4*>(&A[m * 1024 + k0 + ak + 4]);
            const ushort4 u1a = *reinterpret_cast<const ushort4*>(&Ap1[m * 1024 + k0 + ak]);
            const ushort4 u1b = *reinterpret_cast<const ushort4*>(&Ap1[m * 1024 + k0 + ak + 4]);
            short8v t8;
            t8[0] = (short)f2bf((bf2f(u0a.x) * a0 + bf2f(u1a.x) * a1) * inv);
            t8[1] = (short)f2bf((bf2f(u0a.y) * a0 + bf2f(u1a.y) * a1) * inv);
            t8[2] = (short)f2bf((bf2f(u0a.z) * a0 + bf2f(u1a.z) * a1) * inv);
            t8[3] = (short)f2bf((bf2f(u0a.w) * a0 + bf2f(u1a.w) * a1) * inv);
            t8[4] = (short)f2bf((bf2f(u0b.x) * a0 + bf2f(u1b.x) * a1) * inv);
            t8[5] = (short)f2bf((bf2f(u0b.y) * a0 + bf2f(u1b.y) * a1) * inv);
            t8[6] = (short)f2bf((bf2f(u0b.z) * a0 + bf2f(u1b.z) * a1) * inv);
            t8[7] = (short)f2bf((bf2f(u0b.w) * a0 + bf2f(u1b.w) * a1) * inv);
            *reinterpret_cast<short8v*>(&As[tid << 3]) = t8;
        }
        *reinterpret_cast<short8v*>(&Bs[tid << 3]) =
            *reinterpret_cast<const short8v*>(&B[(n0 + ar) * (long)ldb + k0 + ak]);
        __syncthreads();

        short8v af[2], bfv[2];
#pragma unroll
        for (int i = 0; i < 2; ++i) {
            af[i]  = *reinterpret_cast<const short8v*>(&As[(wm + i * 16 + lrow) * 32 + quad * 8]);
            bfv[i] = *reinterpret_cast<const short8v*>(&Bs[(wn + i * 16 + lrow) * 32 + quad * 8]);
        }
#pragma unroll
        for (int mi = 0; mi < 2; ++mi)
#pragma unroll
            for (int ni = 0; ni < 2; ++ni)
                acc[mi][ni] = __builtin_amdgcn_mfma_f32_16x16x32_bf16(
                    af[mi], bfv[ni], acc[mi][ni], 0, 0, 0);
    }

    float* Pz = P + (long)z * NROW * CD;
#pragma unroll
    for (int mi = 0; mi < 2; ++mi)
#pragma unroll
        for (int ni = 0; ni < 2; ++ni) {
            const long col = n0 + wn + ni * 16 + lrow;
            const long row0 = m0 + wm + mi * 16 + quad * 4;
#pragma unroll
            for (int r = 0; r < 4; ++r)
                Pz[(row0 + r) * CD + col] = acc[mi][ni][r];
        }
}

// ---------------------------------------------------------------------------
// mgemm64b: 64x64-tile full-K GEMM, bias(+relu), bf16 out. Grid (N/64, M/64).
// ---------------------------------------------------------------------------
template <int RELU>
__global__ __launch_bounds__(256) void mgemm64b(
    const ushort_t* __restrict__ A, const ushort_t* __restrict__ B,
    const void* __restrict__ bias, ushort_t* __restrict__ C,
    int K, int lda, int ldb, int ldc, long boff,
    const int* __restrict__ flagp)
{
    const long m0 = (long)blockIdx.y * 64;
    const long n0 = (long)blockIdx.x * 64;

    __shared__ __align__(16) ushort_t As[64 * 32];
    __shared__ __align__(16) ushort_t Bs[64 * 32];

    const int tid = threadIdx.x;
    const int wave = tid >> 6;
    const int lane = tid & 63;
    const int quad = lane >> 4;
    const int lrow = lane & 15;
    const int wm = (wave >> 1) * 32;
    const int wn = (wave & 1) * 32;

    const int ar = tid >> 2;
    const int ak = (tid & 3) << 3;

    float4v acc[2][2];
#pragma unroll
    for (int i = 0; i < 2; ++i)
#pragma unroll
        for (int j = 0; j < 2; ++j)
            acc[i][j] = (float4v){0.f, 0.f, 0.f, 0.f};

    for (int k0 = 0; k0 < K; k0 += 32) {
        __syncthreads();
        *reinterpret_cast<short8v*>(&As[tid << 3]) =
            *reinterpret_cast<const short8v*>(&A[(m0 + ar) * (long)lda + k0 + ak]);
        *reinterpret_cast<short8v*>(&Bs[tid << 3]) =
            *reinterpret_cast<const short8v*>(&B[(n0 + ar) * (long)ldb + k0 + ak]);
        __syncthreads();

        short8v af[2], bfv[2];
#pragma unroll
        for (int i = 0; i < 2; ++i) {
            af[i]  = *reinterpret_cast<const short8v*>(&As[(wm + i * 16 + lrow) * 32 + quad * 8]);
            bfv[i] = *reinterpret_cast<const short8v*>(&Bs[(wn + i * 16 + lrow) * 32 + quad * 8]);
        }
#pragma unroll
        for (int mi = 0; mi < 2; ++mi)
#pragma unroll
            for (int ni = 0; ni < 2; ++ni)
                acc[mi][ni] = __builtin_amdgcn_mfma_f32_16x16x32_bf16(
                    af[mi], bfv[ni], acc[mi][ni], 0, 0, 0);
    }

    const int fbf = *flagp;
#pragma unroll
    for (int mi = 0; mi < 2; ++mi)
#pragma unroll
        for (int ni = 0; ni < 2; ++ni) {
            const long col = n0 + wn + ni * 16 + lrow;
            const long row0 = m0 + wm + mi * 16 + quad * 4;
            const float bv = fbf ? bf2f(((const ushort_t*)bias)[boff + col])
                                 : ((const float*)bias)[boff + col];
#pragma unroll
            for (int r = 0; r < 4; ++r) {
                float v = acc[mi][ni][r] + bv;
                if (RELU) v = fmaxf(v, 0.f);
                C[(row0 + r) * (long)ldc + col] = f2bf(v);
            }
        }
}

// ---------------------------------------------------------------------------
// Flash attention v3: 64-key tiles (halved softmax/barrier rounds — round-7
// lesson: the idea was right) but K-ONLY LDS staging (round-7 lesson: 80 KB
// LDS -> 1 block/CU killed it). V fragments read directly from vT via L2
// (bh-swizzle keeps V L2-resident; 4x wave redundancy ~512 MB L2 ~ 15 us).
// LDS = 43 KB -> 3 blocks/CU by LDS; grid 512 = 2/CU resident.
// Skip-rescale: wave-uniform ballot skips the 64-mul oacc rescale when the
// running max didn't move. exp2-domain softmax; unnormalized partials + ml.
// ---------------------------------------------------------------------------
__global__ __launch_bounds__(256) void flash_attn(
    const ushort_t* __restrict__ qk, const ushort_t* __restrict__ vT,
    ushort_t* __restrict__ op0, ushort_t* __restrict__ op1,
    float2* __restrict__ ml)
{
    const int bx = blockIdx.x;
    const int bh = bx & 15;
    const int qt = (bx >> 4) & 15;
    const int ck = bx >> 8;
    const int b = bh >> 2, h = bh & 3;

    __shared__ __align__(16) ushort_t Ks[64 * 264];     // 33792 B
    __shared__ __align__(16) ushort_t Ps[4][16 * 72];   //  9216 B

    const int tid = threadIdx.x;
    const int wave = tid >> 6;
    const int lane = tid & 63;
    const int quad = lane >> 4;
    const int lrow = lane & 15;

    const long qrow0 = (long)b * CT + qt * 64;
    const int qcol = h * 256;
    const int kcol = 1024 + h * 256;
    const long vbase = (long)bh * 256 * 1024;
    const float SC = 0.0625f * LOG2E;

    short8v qf[8];
#pragma unroll
    for (int kk = 0; kk < 8; ++kk)
        qf[kk] = *reinterpret_cast<const short8v*>(
            &qk[(qrow0 + wave * 16 + lrow) * 2048 + qcol + kk * 32 + quad * 8]);

    float m4[4], l4[4];
#pragma unroll
    for (int r = 0; r < 4; ++r) { m4[r] = -1e30f; l4[r] = 0.f; }
    float4v oacc[16];
#pragma unroll
    for (int i = 0; i < 16; ++i) oacc[i] = (float4v){0.f, 0.f, 0.f, 0.f};

    const int t_beg = ck * 512;
    for (int t0 = t_beg; t0 < t_beg + 512; t0 += 64) {
        __syncthreads();
        // stage K 64x256 (2048 16B-chunks, 8/thread)
#pragma unroll
        for (int p = 0; p < 8; ++p) {
            const int c = p * 256 + tid;
            const int r = c >> 5, col = (c & 31) * 8;
            *reinterpret_cast<short8v*>(&Ks[r * 264 + col]) =
                *reinterpret_cast<const short8v*>(
                    &qk[((long)b * CT + t0 + r) * 2048 + kcol + col]);
        }
        __syncthreads();

        // S strip: 16 q-rows x 64 keys, wave-private
        float4v sacc[4];
#pragma unroll
        for (int ni = 0; ni < 4; ++ni)
            sacc[ni] = (float4v){0.f, 0.f, 0.f, 0.f};
#pragma unroll
        for (int kk = 0; kk < 8; ++kk) {
#pragma unroll
            for (int ni = 0; ni < 4; ++ni) {
                short8v bk = *reinterpret_cast<const short8v*>(
                    &Ks[(ni * 16 + lrow) * 264 + kk * 32 + quad * 8]);
                sacc[ni] = __builtin_amdgcn_mfma_f32_16x16x32_bf16(
                    qf[kk], bk, sacc[ni], 0, 0, 0);
            }
        }
#pragma unroll
        for (int ni = 0; ni < 4; ++ni)
#pragma unroll
            for (int r = 0; r < 4; ++r)
                sacc[ni][r] *= SC;

        // online softmax (log2 domain): rows = quad*4+r, reduce over 16 lrow
        float alpha4[4];
#pragma unroll
        for (int r = 0; r < 4; ++r) {
            float mx = fmaxf(fmaxf(sacc[0][r], sacc[1][r]),
                             fmaxf(sacc[2][r], sacc[3][r]));
#pragma unroll
            for (int sh = 1; sh < 16; sh <<= 1)
                mx = fmaxf(mx, __shfl_xor(mx, sh));
            const float mnew = fmaxf(m4[r], mx);
            alpha4[r] = exp2f(m4[r] - mnew);
            m4[r] = mnew;
        }
#pragma unroll
        for (int ni = 0; ni < 4; ++ni)
#pragma unroll
            for (int r = 0; r < 4; ++r) {
                const float pv = exp2f(sacc[ni][r] - m4[r]);
                sacc[ni][r] = pv;
                Ps[wave][(quad * 4 + r) * 72 + ni * 16 + lrow] = f2bf(pv);
            }
#pragma unroll
        for (int r = 0; r < 4; ++r) {
            float s = (sacc[0][r] + sacc[1][r]) + (sacc[2][r] + sacc[3][r]);
#pragma unroll
            for (int sh = 1; sh < 16; sh <<= 1)
                s += __shfl_xor(s, sh);
            l4[r] = l4[r] * alpha4[r] + s;
        }
        // skip-rescale: only pay the 64 muls when some row's max moved
        const float amin = fminf(fminf(alpha4[0], alpha4[1]),
                                 fminf(alpha4[2], alpha4[3]));
        if (__ballot(amin < 1.0f) != 0ull) {
#pragma unroll
            for (int ni = 0; ni < 16; ++ni)
#pragma unroll
                for (int r = 0; r < 4; ++r)
                    oacc[ni][r] *= alpha4[r];
        }

        // O += P(16x64) @ V(64x256); V B-frags straight from global (L2)
#pragma unroll
        for (int s = 0; s < 2; ++s) {
            short8v ap = *reinterpret_cast<const short8v*>(
                &Ps[wave][lrow * 72 + s * 32 + quad * 8]);
#pragma unroll
            for (int ni = 0; ni < 16; ++ni) {
                short8v bv = *reinterpret_cast<const short8v*>(
                    &vT[vbase + (long)(ni * 16 + lrow) * 1024 + t0 + s * 32 + quad * 8]);
                oacc[ni] = __builtin_amdgcn_mfma_f32_16x16x32_bf16(
                    ap, bv, oacc[ni], 0, 0, 0);
            }
        }
    }

    // epilogue: unnormalized partial O + (m,l) (log2-units)
#pragma unroll
    for (int r = 0; r < 4; ++r)
        if (lrow == 0)
            ml[((ck << 4) + bh) * 1024 + qt * 64 + wave * 16 + quad * 4 + r] =
                make_float2(m4[r], l4[r]);

    ushort_t* op = ck ? op1 : op0;
#pragma unroll
    for (int ni = 0; ni < 16; ++ni)
#pragma unroll
        for (int r = 0; r < 4; ++r)
            op[(qrow0 + wave * 16 + quad * 4 + r) * 1024 + (h << 8) + ni * 16 + lrow]
                = f2bf(oacc[ni][r]);
}

// ---------------------------------------------------------------------------
// ln_p: x = P0[row]+P1[row] + gbias + res; out = LN(x)*s + b (bf16).
// ---------------------------------------------------------------------------
__global__ __launch_bounds__(256) void ln_p(
    const float* __restrict__ p, const void* __restrict__ gb, long gboff,
    const ushort_t* __restrict__ res, const void* __restrict__ sc,
    const void* __restrict__ bi, ushort_t* __restrict__ out, long loff,
    const int* __restrict__ flagp)
{
    const int fbf = *flagp;
    const long row = (long)blockIdx.x * CD;
    const int t = threadIdx.x;
    const float gbv = fbf ? bf2f(((const ushort_t*)gb)[gboff + t])
                          : ((const float*)gb)[gboff + t];
    const float x = p[row + t] + p[(long)NROW * CD + row + t] + gbv + bf2f(res[row + t]);

    __shared__ float r1[256];
    __shared__ float r2[256];
    r1[t] = x;
    r2[t] = x * x;
    __syncthreads();
    for (int s = 128; s > 0; s >>= 1) {
        if (t < s) { r1[t] += r1[t + s]; r2[t] += r2[t + s]; }
        __syncthreads();
    }
    const float mean = r1[0] * (1.0f / CD);
    const float var = r2[0] * (1.0f / CD) - mean * mean;
    const float rstd = rsqrtf(var + 1e-5f);
    const float s_v = fbf ? bf2f(((const ushort_t*)sc)[loff + t]) : ((const float*)sc)[loff + t];
    const float b_v = fbf ? bf2f(((const ushort_t*)bi)[loff + t]) : ((const float*)bi)[loff + t];
    out[row + t] = f2bf((x - mean) * rstd * s_v + b_v);
}

__global__ __launch_bounds__(256) void in_convert(
    const void* __restrict__ in, ushort_t* __restrict__ x,
    const int* __restrict__ flagp)
{
    const int fbf = *flagp;
    const long i = ((long)blockIdx.x * 256 + threadIdx.x) << 2;
    if (fbf) {
        *reinterpret_cast<ushort4*>(x + i) =
            *reinterpret_cast<const ushort4*>((const ushort_t*)in + i);
    } else {
        float4 f = *reinterpret_cast<const float4*>((const float*)in + i);
        ushort4 u;
        u.x = f2bf(f.x); u.y = f2bf(f.y); u.z = f2bf(f.z); u.w = f2bf(f.w);
        *reinterpret_cast<ushort4*>(x + i) = u;
    }
}

__global__ __launch_bounds__(256) void out_write(
    const ushort_t* __restrict__ x, void* __restrict__ out,
    const int* __restrict__ flagp)
{
    const int fbf = *flagp;
    const long i = ((long)blockIdx.x * 256 + threadIdx.x) << 2;
    ushort4 u = *reinterpret_cast<const ushort4*>(x + i);
    if (fbf) {
        *reinterpret_cast<ushort4*>((ushort_t*)out + i) = u;
    } else {
        float4 f = make_float4(bf2f(u.x), bf2f(u.y), bf2f(u.z), bf2f(u.w));
        *reinterpret_cast<float4*>((float*)out + i) = f;
    }
}

// ---------------------------------------------------------------------------
// Orchestration. ws = 46.75 MB (< 48 known-safe).
// ---------------------------------------------------------------------------
extern "C" void kernel_launch(void* const* d_in, const int* in_sizes, int n_in,
                              void* d_out, int out_size, void* d_ws, size_t ws_size,
                              hipStream_t stream)
{
    const void* queries = d_in[0];
    const void* Wq = d_in[1];  const void* bq = d_in[2];
    const void* Wk = d_in[3];  const void* bk = d_in[4];
    const void* Wv = d_in[5];  const void* bv = d_in[6];
    const void* Wo = d_in[7];  const void* bo = d_in[8];
    const void* ln1s = d_in[9];  const void* ln1b = d_in[10];
    const void* W1 = d_in[11]; const void* b1 = d_in[12];
    const void* W2 = d_in[13]; const void* b2 = d_in[14];
    const void* ln2s = d_in[15]; const void* ln2b = d_in[16];

    char* p = (char*)d_ws;
    int* flagp = (int*)p;             p += 256;
    ushort_t* wqkvT = (ushort_t*)p;   p += (long)CL * 3072 * 256 * 2;  // 3 MB
    ushort_t* w1T   = (ushort_t*)p;   p += (long)CL * 1024 * 256 * 2;  // 1 MB
    ushort_t* wscr  = (ushort_t*)p;   p += (long)256 * 1024 * 2;       // 0.5 MB
    ushort_t* xa    = (ushort_t*)p;   p += (long)NROW * CD * 2;        // 2 MB
    ushort_t* qk    = (ushort_t*)p;   p += (long)NROW * 2048 * 2;      // 16 MB
    ushort_t* vT    = (ushort_t*)p;   p += (long)16 * 256 * 1024 * 2;  // 8 MB
    ushort_t* op0   = (ushort_t*)p;   p += (long)NROW * 1024 * 2;      // 8 MB
    ushort_t* op1   = (ushort_t*)p;   p += (long)NROW * 1024 * 2;      // 8 MB
    float2*   ml    = (float2*)p;     p += (long)2 * 16 * 1024 * 8;    // 0.25 MB
    ushort_t* h     = vT;             // MLP hidden reuses vT
    float*    pgem  = (float*)qk;     // fp32 partials reuse qk (dead post-flash)

    detect_kernel<<<1, 256, 0, stream>>>((const ushort_t*)Wq, 2048, flagp);

    // wqkvT[l] = [3072][256]: rows 0..1023 WqT | 1024..2047 WkT | 2048.. WvT
    tconv_kernel<<<dim3(32, 8, CL), 256, 0, stream>>>(
        Wq, wqkvT, 256, 1024, 256 * 1024, 3072 * 256, 0, flagp);
    tconv_kernel<<<dim3(32, 8, CL), 256, 0, stream>>>(
        Wk, wqkvT + 1024 * 256, 256, 1024, 256 * 1024, 3072 * 256, 0, flagp);
    tconv_kernel<<<dim3(32, 8, CL), 256, 0, stream>>>(
        Wv, wqkvT + 2048 * 256, 256, 1024, 256 * 1024, 3072 * 256, 0, flagp);
    tconv_kernel<<<dim3(32, 8, CL), 256, 0, stream>>>(
        W1, w1T, 256, 1024, 256 * 1024, 1024 * 256, 0, flagp);

    in_convert<<<(NROW * CD) / 1024, 256, 0, stream>>>(queries, xa, flagp);

    for (int l = 0; l < CL; ++l) {
        // 1) merged QKV projection -> qk [4096,2048] + vT[bh][d][t]
        qkv_proj<<<dim3(24, 32, 1), 256, 0, stream>>>(
            xa, wqkvT + (long)l * 3072 * 256, bq, bk, bv, qk, vT,
            (long)l * 1024, flagp);
        // 2) Wo^T -> wscr
        tconv_kernel<<<dim3(8, 32, 1), 256, 0, stream>>>(
            Wo, wscr, 1024, 256, 0, 0, (long)l * 1024 * 256, flagp);
        // 3) flash attention (512 blocks, 64-key tiles, K-only LDS)
        flash_attn<<<512, 256, 0, stream>>>(qk, vT, op0, op1, ml);
        // 4) O projection with fused partial-combine -> fp32 pgem
        mgemm64s<1><<<dim3(4, 64, 2), 256, 0, stream>>>(
            op0, op1, ml, wscr, pgem, 512, 1024, 1024);
        // 5) xa = LN(pgem0+pgem1 + bo + xa)
        ln_p<<<NROW, 256, 0, stream>>>(pgem, bo, (long)l * 256, xa,
                                       ln1s, ln1b, xa, (long)l * 256, flagp);
        // 6) h = relu(xa @ w1T^T + b1)  (1024 blocks = 4/CU)
        mgemm64b<1><<<dim3(16, 64, 1), 256, 0, stream>>>(
            xa, w1T + (long)l * 1024 * 256, b1, h,
            256, 256, 256, 1024, (long)l * 1024, flagp);
        // 7) W2^T -> wscr
        tconv_kernel<<<dim3(8, 32, 1), 256, 0, stream>>>(
            W2, wscr, 1024, 256, 0, 0, (long)l * 1024 * 256, flagp);
        // 8) MLP2 -> fp32 pgem
        mgemm64s<0><<<dim3(4, 64, 2), 256, 0, stream>>>(
            h, nullptr, nullptr, wscr, pgem, 512, 1024, 1024);
        // 9) xa = LN(pgem0+pgem1 + b2 + xa)
        ln_p<<<NROW, 256, 0, stream>>>(pgem, b2, (long)l * 256, xa,
                                       ln2s, ln2b, xa, (long)l * 256, flagp);
    }

    out_write<<<(NROW * CD) / 1024, 256, 0, stream>>>(xa, d_out, flagp);
}

// Round 9
// 347.978 us; speedup vs baseline: 1.4932x; 1.3113x over previous
//
#include <hip/hip_runtime.h>
#include <hip/hip_bf16.h>

#define CL 2
#define CB 4
#define CT 1024
#define CD 256
#define CH 4
#define CM 1024
#define CHD (CH * CD)      // 1024
#define NROW (CB * CT)     // 4096

typedef unsigned short ushort_t;
typedef __attribute__((ext_vector_type(8))) short short8v;   // 8 bf16 (4 VGPR)
typedef __attribute__((ext_vector_type(4))) float float4v;   // MFMA C/D frag

#define LOG2E 1.44269504088896f

__device__ __forceinline__ float bf2f(unsigned short u) {
    return __uint_as_float(((unsigned int)u) << 16);
}
__device__ __forceinline__ unsigned short f2bf(float f) {
    unsigned int x = __float_as_uint(f);
    return (unsigned short)((x + 0x7fffu + ((x >> 16) & 1u)) >> 16);
}

// ---------------------------------------------------------------------------
// Input-dtype detection (2048 elems; fp32-underlying -> ~430 anomalies, bf16 0)
// ---------------------------------------------------------------------------
__global__ __launch_bounds__(256) void detect_kernel(
    const ushort_t* __restrict__ w, int n, int* __restrict__ flag)
{
    __shared__ int red[256];
    int c = 0;
    for (int i = threadIdx.x; i < n; i += 256) {
        float v = bf2f(w[i]);
        if (!(fabsf(v) <= 1e6f)) c++;
    }
    red[threadIdx.x] = c;
    __syncthreads();
    for (int s = 128; s > 0; s >>= 1) {
        if (threadIdx.x < s) red[threadIdx.x] += red[threadIdx.x + s];
        __syncthreads();
    }
    if (threadIdx.x == 0) flag[0] = (red[0] < 8) ? 1 : 0;
}

// ---------------------------------------------------------------------------
// Weight transpose+convert: in [Z][R][C] (+ioff elems, dtype per flag) ->
// out bf16 [Z][C][R].
// ---------------------------------------------------------------------------
__global__ __launch_bounds__(256) void tconv_kernel(
    const void* __restrict__ in, ushort_t* __restrict__ out,
    int R, int C, long inzs, long outzs, long ioff,
    const int* __restrict__ flagp)
{
    const int fbf = *flagp;
    __shared__ float tile[32][33];
    const long zi = ioff + (long)blockIdx.z * inzs;
    const long zo = (long)blockIdx.z * outzs;
    const int r0 = blockIdx.y * 32;
    const int c0 = blockIdx.x * 32;
    const int tx = threadIdx.x & 31;
    const int ty = threadIdx.x >> 5;
#pragma unroll
    for (int i = 0; i < 32; i += 8) {
        const long idx = zi + (long)(r0 + ty + i) * C + c0 + tx;
        tile[ty + i][tx] = fbf ? bf2f(((const ushort_t*)in)[idx])
                               : ((const float*)in)[idx];
    }
    __syncthreads();
#pragma unroll
    for (int i = 0; i < 32; i += 8)
        out[zo + (long)(c0 + ty + i) * R + r0 + tx] = f2bf(tile[tx][ty + i]);
}

// ---------------------------------------------------------------------------
// QKV projection (merged, verified r7/r8): A = xa [4096][256];
// B = wqkvT[l] [3072][256]. 128x128 tiles, grid (24,32)=768 blocks.
// cols<2048 -> qk row-major; cols>=2048 -> V transposed into vT[bh][d][t].
// ---------------------------------------------------------------------------
__global__ __launch_bounds__(256) void qkv_proj(
    const ushort_t* __restrict__ A, const ushort_t* __restrict__ B,
    const void* __restrict__ bq, const void* __restrict__ bk,
    const void* __restrict__ bv, ushort_t* __restrict__ qk,
    ushort_t* __restrict__ vT, long boff, const int* __restrict__ flagp)
{
    const long m0 = (long)blockIdx.y * 128;
    const long n0 = (long)blockIdx.x * 128;

    __shared__ __align__(16) ushort_t As[128 * 32];
    __shared__ __align__(16) ushort_t Bs[128 * 32];

    const int tid = threadIdx.x;
    const int wave = tid >> 6;
    const int lane = tid & 63;
    const int quad = lane >> 4;
    const int lrow = lane & 15;
    const int wm = (wave >> 1) * 64;
    const int wn = (wave & 1) * 64;

    float4v acc[4][4];
#pragma unroll
    for (int i = 0; i < 4; ++i)
#pragma unroll
        for (int j = 0; j < 4; ++j)
            acc[i][j] = (float4v){0.f, 0.f, 0.f, 0.f};

    for (int k0 = 0; k0 < 256; k0 += 32) {
        __syncthreads();
#pragma unroll
        for (int p = 0; p < 2; ++p) {
            const int c = p * 256 + tid;
            const int row = c >> 2;
            const int kk = (c & 3) << 3;
            *reinterpret_cast<short8v*>(&As[c << 3]) =
                *reinterpret_cast<const short8v*>(&A[(m0 + row) * 256 + k0 + kk]);
            *reinterpret_cast<short8v*>(&Bs[c << 3]) =
                *reinterpret_cast<const short8v*>(&B[(n0 + row) * 256 + k0 + kk]);
        }
        __syncthreads();

        short8v af[4], bfv[4];
#pragma unroll
        for (int i = 0; i < 4; ++i) {
            af[i]  = *reinterpret_cast<const short8v*>(&As[(wm + i * 16 + lrow) * 32 + quad * 8]);
            bfv[i] = *reinterpret_cast<const short8v*>(&Bs[(wn + i * 16 + lrow) * 32 + quad * 8]);
        }
#pragma unroll
        for (int mi = 0; mi < 4; ++mi)
#pragma unroll
            for (int ni = 0; ni < 4; ++ni)
                acc[mi][ni] = __builtin_amdgcn_mfma_f32_16x16x32_bf16(
                    af[mi], bfv[ni], acc[mi][ni], 0, 0, 0);
    }

    const int fbf = *flagp;
#pragma unroll
    for (int mi = 0; mi < 4; ++mi) {
#pragma unroll
        for (int ni = 0; ni < 4; ++ni) {
            const long col = n0 + wn + ni * 16 + lrow;
            const long row0 = m0 + wm + mi * 16 + quad * 4;
            const void* bp;
            long bn;
            if (col < 1024)      { bp = bq; bn = col; }
            else if (col < 2048) { bp = bk; bn = col - 1024; }
            else                 { bp = bv; bn = col - 2048; }
            const float bias = fbf ? bf2f(((const ushort_t*)bp)[boff + bn])
                                   : ((const float*)bp)[boff + bn];
            if (col < 2048) {
#pragma unroll
                for (int r = 0; r < 4; ++r)
                    qk[(row0 + r) * 2048 + col] = f2bf(acc[mi][ni][r] + bias);
            } else {
                const long d = col - 2048;
                const long addr = ((row0 >> 10) << 2) * 262144 + d * 1024 + (row0 & 1023);
                ushort4 u;
                u.x = f2bf(acc[mi][ni][0] + bias);
                u.y = f2bf(acc[mi][ni][1] + bias);
                u.z = f2bf(acc[mi][ni][2] + bias);
                u.w = f2bf(acc[mi][ni][3] + bias);
                *reinterpret_cast<ushort4*>(&vT[addr]) = u;
            }
        }
    }
}

// ---------------------------------------------------------------------------
// mgemm64s: 64x64-tile split-K GEMM -> fp32 partials. Grid (N/64, M/64, 2).
// AMODE 0: plain bf16 A. AMODE 1: combined attention partials (exp2 domain).
// ---------------------------------------------------------------------------
template <int AMODE>
__global__ __launch_bounds__(256) void mgemm64s(
    const ushort_t* __restrict__ A, const ushort_t* __restrict__ Ap1,
    const float2* __restrict__ ml, const ushort_t* __restrict__ B,
    float* __restrict__ P, int K2, int lda, int ldb)
{
    const int z = blockIdx.z;
    const long m0 = (long)blockIdx.y * 64;
    const long n0 = (long)blockIdx.x * 64;
    const int k_beg = z * K2;

    __shared__ __align__(16) ushort_t As[64 * 32];
    __shared__ __align__(16) ushort_t Bs[64 * 32];

    const int tid = threadIdx.x;
    const int wave = tid >> 6;
    const int lane = tid & 63;
    const int quad = lane >> 4;
    const int lrow = lane & 15;
    const int wm = (wave >> 1) * 32;
    const int wn = (wave & 1) * 32;

    const int ar = tid >> 2;
    const int ak = (tid & 3) << 3;

    float4v acc[2][2];
#pragma unroll
    for (int i = 0; i < 2; ++i)
#pragma unroll
        for (int j = 0; j < 2; ++j)
            acc[i][j] = (float4v){0.f, 0.f, 0.f, 0.f};

    for (int k0 = k_beg; k0 < k_beg + K2; k0 += 32) {
        __syncthreads();
        if constexpr (AMODE == 0) {
            *reinterpret_cast<short8v*>(&As[tid << 3]) =
                *reinterpret_cast<const short8v*>(&A[(m0 + ar) * (long)lda + k0 + ak]);
        } else {
            const long m = m0 + ar;
            const int hh = (k0 + ak) >> 8;
            const int bh = ((int)(m >> 10) << 2) + hh;
            const int trow = (int)(m & 1023);
            const float2 v0 = ml[bh * 1024 + trow];
            const float2 v1 = ml[(16 + bh) * 1024 + trow];
            const float mm = fmaxf(v0.x, v1.x);
            const float a0 = exp2f(v0.x - mm);
            const float a1 = exp2f(v1.x - mm);
            const float inv = 1.0f / (v0.y * a0 + v1.y * a1);
            const ushort4 u0a = *reinterpret_cast<const ushort4*>(&A[m * 1024 + k0 + ak]);
            const ushort4 u0b = *reinterpret_cast<const ushort4*>(&A[m * 1024 + k0 + ak + 4]);
            const ushort4 u1a = *reinterpret_cast<const ushort4*>(&Ap1[m * 1024 + k0 + ak]);
            const ushort4 u1b = *reinterpret_cast<const ushort4*>(&Ap1[m * 1024 + k0 + ak + 4]);
            short8v t8;
            t8[0] = (short)f2bf((bf2f(u0a.x) * a0 + bf2f(u1a.x) * a1) * inv);
            t8[1] = (short)f2bf((bf2f(u0a.y) * a0 + bf2f(u1a.y) * a1) * inv);
            t8[2] = (short)f2bf((bf2f(u0a.z) * a0 + bf2f(u1a.z) * a1) * inv);
            t8[3] = (short)f2bf((bf2f(u0a.w) * a0 + bf2f(u1a.w) * a1) * inv);
            t8[4] = (short)f2bf((bf2f(u0b.x) * a0 + bf2f(u1b.x) * a1) * inv);
            t8[5] = (short)f2bf((bf2f(u0b.y) * a0 + bf2f(u1b.y) * a1) * inv);
            t8[6] = (short)f2bf((bf2f(u0b.z) * a0 + bf2f(u1b.z) * a1) * inv);
            t8[7] = (short)f2bf((bf2f(u0b.w) * a0 + bf2f(u1b.w) * a1) * inv);
            *reinterpret_cast<short8v*>(&As[tid << 3]) = t8;
        }
        *reinterpret_cast<short8v*>(&Bs[tid << 3]) =
            *reinterpret_cast<const short8v*>(&B[(n0 + ar) * (long)ldb + k0 + ak]);
        __syncthreads();

        short8v af[2], bfv[2];
#pragma unroll
        for (int i = 0; i < 2; ++i) {
            af[i]  = *reinterpret_cast<const short8v*>(&As[(wm + i * 16 + lrow) * 32 + quad * 8]);
            bfv[i] = *reinterpret_cast<const short8v*>(&Bs[(wn + i * 16 + lrow) * 32 + quad * 8]);
        }
#pragma unroll
        for (int mi = 0; mi < 2; ++mi)
#pragma unroll
            for (int ni = 0; ni < 2; ++ni)
                acc[mi][ni] = __builtin_amdgcn_mfma_f32_16x16x32_bf16(
                    af[mi], bfv[ni], acc[mi][ni], 0, 0, 0);
    }

    float* Pz = P + (long)z * NROW * CD;
#pragma unroll
    for (int mi = 0; mi < 2; ++mi)
#pragma unroll
        for (int ni = 0; ni < 2; ++ni) {
            const long col = n0 + wn + ni * 16 + lrow;
            const long row0 = m0 + wm + mi * 16 + quad * 4;
#pragma unroll
            for (int r = 0; r < 4; ++r)
                Pz[(row0 + r) * CD + col] = acc[mi][ni][r];
        }
}

// ---------------------------------------------------------------------------
// mgemm64b: 64x64-tile full-K GEMM, bias(+relu), bf16 out. Grid (N/64, M/64).
// ---------------------------------------------------------------------------
template <int RELU>
__global__ __launch_bounds__(256) void mgemm64b(
    const ushort_t* __restrict__ A, const ushort_t* __restrict__ B,
    const void* __restrict__ bias, ushort_t* __restrict__ C,
    int K, int lda, int ldb, int ldc, long boff,
    const int* __restrict__ flagp)
{
    const long m0 = (long)blockIdx.y * 64;
    const long n0 = (long)blockIdx.x * 64;

    __shared__ __align__(16) ushort_t As[64 * 32];
    __shared__ __align__(16) ushort_t Bs[64 * 32];

    const int tid = threadIdx.x;
    const int wave = tid >> 6;
    const int lane = tid & 63;
    const int quad = lane >> 4;
    const int lrow = lane & 15;
    const int wm = (wave >> 1) * 32;
    const int wn = (wave & 1) * 32;

    const int ar = tid >> 2;
    const int ak = (tid & 3) << 3;

    float4v acc[2][2];
#pragma unroll
    for (int i = 0; i < 2; ++i)
#pragma unroll
        for (int j = 0; j < 2; ++j)
            acc[i][j] = (float4v){0.f, 0.f, 0.f, 0.f};

    for (int k0 = 0; k0 < K; k0 += 32) {
        __syncthreads();
        *reinterpret_cast<short8v*>(&As[tid << 3]) =
            *reinterpret_cast<const short8v*>(&A[(m0 + ar) * (long)lda + k0 + ak]);
        *reinterpret_cast<short8v*>(&Bs[tid << 3]) =
            *reinterpret_cast<const short8v*>(&B[(n0 + ar) * (long)ldb + k0 + ak]);
        __syncthreads();

        short8v af[2], bfv[2];
#pragma unroll
        for (int i = 0; i < 2; ++i) {
            af[i]  = *reinterpret_cast<const short8v*>(&As[(wm + i * 16 + lrow) * 32 + quad * 8]);
            bfv[i] = *reinterpret_cast<const short8v*>(&Bs[(wn + i * 16 + lrow) * 32 + quad * 8]);
        }
#pragma unroll
        for (int mi = 0; mi < 2; ++mi)
#pragma unroll
            for (int ni = 0; ni < 2; ++ni)
                acc[mi][ni] = __builtin_amdgcn_mfma_f32_16x16x32_bf16(
                    af[mi], bfv[ni], acc[mi][ni], 0, 0, 0);
    }

    const int fbf = *flagp;
#pragma unroll
    for (int mi = 0; mi < 2; ++mi)
#pragma unroll
        for (int ni = 0; ni < 2; ++ni) {
            const long col = n0 + wn + ni * 16 + lrow;
            const long row0 = m0 + wm + mi * 16 + quad * 4;
            const float bv = fbf ? bf2f(((const ushort_t*)bias)[boff + col])
                                 : ((const float*)bias)[boff + col];
#pragma unroll
            for (int r = 0; r < 4; ++r) {
                float v = acc[mi][ni][r] + bv;
                if (RELU) v = fmaxf(v, 0.f);
                C[(row0 + r) * (long)ldc + col] = f2bf(v);
            }
        }
}

// ---------------------------------------------------------------------------
// Flash attention v4 = round-6 structure EXACTLY (proven 54.7 us: 32-key
// tiles, K AND V staged in LDS 42.5 KB -> 2 blocks/CU; r7's 80 KB and r8's
// V-from-global both regressed) + the numerically-neutral r7/r8 additions:
// exp2-domain softmax and ballot skip-rescale. KV-split x2; unnormalized
// partials + (m,l) in log2-units; qk read-only.
// ---------------------------------------------------------------------------
__global__ __launch_bounds__(256) void flash_attn(
    const ushort_t* __restrict__ qk, const ushort_t* __restrict__ vT,
    ushort_t* __restrict__ op0, ushort_t* __restrict__ op1,
    float2* __restrict__ ml)
{
    const int bx = blockIdx.x;
    const int bh = bx & 15;
    const int qt = (bx >> 4) & 15;
    const int ck = bx >> 8;
    const int b = bh >> 2, h = bh & 3;

    __shared__ __align__(16) ushort_t Ks[32 * 264];     // 16896 B
    __shared__ __align__(16) ushort_t Vs[256 * 40];     // 20480 B
    __shared__ __align__(16) ushort_t Ps[4][16 * 40];   //  5120 B

    const int tid = threadIdx.x;
    const int wave = tid >> 6;
    const int lane = tid & 63;
    const int quad = lane >> 4;
    const int lrow = lane & 15;

    const long qrow0 = (long)b * CT + qt * 64;
    const int qcol = h * 256;
    const int kcol = 1024 + h * 256;
    const long vbase = (long)bh * 256 * 1024;
    const float SC = 0.0625f * LOG2E;

    short8v qf[8];
#pragma unroll
    for (int kk = 0; kk < 8; ++kk)
        qf[kk] = *reinterpret_cast<const short8v*>(
            &qk[(qrow0 + wave * 16 + lrow) * 2048 + qcol + kk * 32 + quad * 8]);

    float m4[4], l4[4];
#pragma unroll
    for (int r = 0; r < 4; ++r) { m4[r] = -1e30f; l4[r] = 0.f; }
    float4v oacc[16];
#pragma unroll
    for (int i = 0; i < 16; ++i) oacc[i] = (float4v){0.f, 0.f, 0.f, 0.f};

    const int t_beg = ck * 512;
    for (int t0 = t_beg; t0 < t_beg + 512; t0 += 32) {
        __syncthreads();
        // stage K 32x256 and V 256x32 (1024 16B-chunks each, 4/thread each)
#pragma unroll
        for (int p = 0; p < 4; ++p) {
            const int c = p * 256 + tid;
            {
                const int r = c >> 5, col = (c & 31) * 8;
                *reinterpret_cast<short8v*>(&Ks[r * 264 + col]) =
                    *reinterpret_cast<const short8v*>(
                        &qk[((long)b * CT + t0 + r) * 2048 + kcol + col]);
            }
            {
                const int r = c >> 2, col = (c & 3) * 8;
                *reinterpret_cast<short8v*>(&Vs[r * 40 + col]) =
                    *reinterpret_cast<const short8v*>(
                        &vT[vbase + (long)r * 1024 + t0 + col]);
            }
        }
        __syncthreads();

        // S strip: 16 q-rows x 32 keys, wave-private
        float4v sacc[2];
        sacc[0] = (float4v){0.f, 0.f, 0.f, 0.f};
        sacc[1] = (float4v){0.f, 0.f, 0.f, 0.f};
#pragma unroll
        for (int kk = 0; kk < 8; ++kk) {
#pragma unroll
            for (int ni = 0; ni < 2; ++ni) {
                short8v bk = *reinterpret_cast<const short8v*>(
                    &Ks[(ni * 16 + lrow) * 264 + kk * 32 + quad * 8]);
                sacc[ni] = __builtin_amdgcn_mfma_f32_16x16x32_bf16(
                    qf[kk], bk, sacc[ni], 0, 0, 0);
            }
        }
#pragma unroll
        for (int ni = 0; ni < 2; ++ni)
#pragma unroll
            for (int r = 0; r < 4; ++r)
                sacc[ni][r] *= SC;

        // online softmax (log2 domain): rows = quad*4+r, reduce over 16 lrow
        float alpha4[4];
#pragma unroll
        for (int r = 0; r < 4; ++r) {
            float mx = fmaxf(sacc[0][r], sacc[1][r]);
#pragma unroll
            for (int sh = 1; sh < 16; sh <<= 1)
                mx = fmaxf(mx, __shfl_xor(mx, sh));
            const float mnew = fmaxf(m4[r], mx);
            alpha4[r] = exp2f(m4[r] - mnew);
            m4[r] = mnew;
        }
#pragma unroll
        for (int ni = 0; ni < 2; ++ni)
#pragma unroll
            for (int r = 0; r < 4; ++r) {
                const float pv = exp2f(sacc[ni][r] - m4[r]);
                sacc[ni][r] = pv;
                Ps[wave][(quad * 4 + r) * 40 + ni * 16 + lrow] = f2bf(pv);
            }
#pragma unroll
        for (int r = 0; r < 4; ++r) {
            float s = sacc[0][r] + sacc[1][r];
#pragma unroll
            for (int sh = 1; sh < 16; sh <<= 1)
                s += __shfl_xor(s, sh);
            l4[r] = l4[r] * alpha4[r] + s;
        }
        // skip-rescale: only pay the 64 muls when some row's max moved
        const float amin = fminf(fminf(alpha4[0], alpha4[1]),
                                 fminf(alpha4[2], alpha4[3]));
        if (__ballot(amin < 1.0f) != 0ull) {
#pragma unroll
            for (int ni = 0; ni < 16; ++ni)
#pragma unroll
                for (int r = 0; r < 4; ++r)
                    oacc[ni][r] *= alpha4[r];
        }

        // O += P(16x32) @ V(32x256): A = Ps, B = Vs[d][t]
        {
            short8v ap = *reinterpret_cast<const short8v*>(
                &Ps[wave][lrow * 40 + quad * 8]);
#pragma unroll
            for (int ni = 0; ni < 16; ++ni) {
                short8v bv = *reinterpret_cast<const short8v*>(
                    &Vs[(ni * 16 + lrow) * 40 + quad * 8]);
                oacc[ni] = __builtin_amdgcn_mfma_f32_16x16x32_bf16(
                    ap, bv, oacc[ni], 0, 0, 0);
            }
        }
    }

    // epilogue: unnormalized partial O + (m,l) (log2-units)
#pragma unroll
    for (int r = 0; r < 4; ++r)
        if (lrow == 0)
            ml[((ck << 4) + bh) * 1024 + qt * 64 + wave * 16 + quad * 4 + r] =
                make_float2(m4[r], l4[r]);

    ushort_t* op = ck ? op1 : op0;
#pragma unroll
    for (int ni = 0; ni < 16; ++ni)
#pragma unroll
        for (int r = 0; r < 4; ++r)
            op[(qrow0 + wave * 16 + quad * 4 + r) * 1024 + (h << 8) + ni * 16 + lrow]
                = f2bf(oacc[ni][r]);
}

// ---------------------------------------------------------------------------
// ln_p: x = P0[row]+P1[row] + gbias + res; y = LN(x)*s + b.
// FINAL=0: write bf16 to out. FINAL=1: write d_out in flag dtype (fuses the
// old out_write dispatch).
// ---------------------------------------------------------------------------
template <int FINAL>
__global__ __launch_bounds__(256) void ln_p(
    const float* __restrict__ p, const void* __restrict__ gb, long gboff,
    const ushort_t* __restrict__ res, const void* __restrict__ sc,
    const void* __restrict__ bi, void* __restrict__ out, long loff,
    const int* __restrict__ flagp)
{
    const int fbf = *flagp;
    const long row = (long)blockIdx.x * CD;
    const int t = threadIdx.x;
    const float gbv = fbf ? bf2f(((const ushort_t*)gb)[gboff + t])
                          : ((const float*)gb)[gboff + t];
    const float x = p[row + t] + p[(long)NROW * CD + row + t] + gbv + bf2f(res[row + t]);

    __shared__ float r1[256];
    __shared__ float r2[256];
    r1[t] = x;
    r2[t] = x * x;
    __syncthreads();
    for (int s = 128; s > 0; s >>= 1) {
        if (t < s) { r1[t] += r1[t + s]; r2[t] += r2[t + s]; }
        __syncthreads();
    }
    const float mean = r1[0] * (1.0f / CD);
    const float var = r2[0] * (1.0f / CD) - mean * mean;
    const float rstd = rsqrtf(var + 1e-5f);
    const float s_v = fbf ? bf2f(((const ushort_t*)sc)[loff + t]) : ((const float*)sc)[loff + t];
    const float b_v = fbf ? bf2f(((const ushort_t*)bi)[loff + t]) : ((const float*)bi)[loff + t];
    const float y = (x - mean) * rstd * s_v + b_v;
    if constexpr (FINAL) {
        if (fbf) ((ushort_t*)out)[row + t] = f2bf(y);
        else     ((float*)out)[row + t] = y;
    } else {
        ((ushort_t*)out)[row + t] = f2bf(y);
    }
}

__global__ __launch_bounds__(256) void in_convert(
    const void* __restrict__ in, ushort_t* __restrict__ x,
    const int* __restrict__ flagp)
{
    const int fbf = *flagp;
    const long i = ((long)blockIdx.x * 256 + threadIdx.x) << 2;
    if (fbf) {
        *reinterpret_cast<ushort4*>(x + i) =
            *reinterpret_cast<const ushort4*>((const ushort_t*)in + i);
    } else {
        float4 f = *reinterpret_cast<const float4*>((const float*)in + i);
        ushort4 u;
        u.x = f2bf(f.x); u.y = f2bf(f.y); u.z = f2bf(f.z); u.w = f2bf(f.w);
        *reinterpret_cast<ushort4*>(x + i) = u;
    }
}

// ---------------------------------------------------------------------------
// Orchestration. ws = 46.75 MB (< 48 known-safe).
// ---------------------------------------------------------------------------
extern "C" void kernel_launch(void* const* d_in, const int* in_sizes, int n_in,
                              void* d_out, int out_size, void* d_ws, size_t ws_size,
                              hipStream_t stream)
{
    const void* queries = d_in[0];
    const void* Wq = d_in[1];  const void* bq = d_in[2];
    const void* Wk = d_in[3];  const void* bk = d_in[4];
    const void* Wv = d_in[5];  const void* bv = d_in[6];
    const void* Wo = d_in[7];  const void* bo = d_in[8];
    const void* ln1s = d_in[9];  const void* ln1b = d_in[10];
    const void* W1 = d_in[11]; const void* b1 = d_in[12];
    const void* W2 = d_in[13]; const void* b2 = d_in[14];
    const void* ln2s = d_in[15]; const void* ln2b = d_in[16];

    char* p = (char*)d_ws;
    int* flagp = (int*)p;             p += 256;
    ushort_t* wqkvT = (ushort_t*)p;   p += (long)CL * 3072 * 256 * 2;  // 3 MB
    ushort_t* w1T   = (ushort_t*)p;   p += (long)CL * 1024 * 256 * 2;  // 1 MB
    ushort_t* wscr  = (ushort_t*)p;   p += (long)256 * 1024 * 2;       // 0.5 MB
    ushort_t* xa    = (ushort_t*)p;   p += (long)NROW * CD * 2;        // 2 MB
    ushort_t* qk    = (ushort_t*)p;   p += (long)NROW * 2048 * 2;      // 16 MB
    ushort_t* vT    = (ushort_t*)p;   p += (long)16 * 256 * 1024 * 2;  // 8 MB
    ushort_t* op0   = (ushort_t*)p;   p += (long)NROW * 1024 * 2;      // 8 MB
    ushort_t* op1   = (ushort_t*)p;   p += (long)NROW * 1024 * 2;      // 8 MB
    float2*   ml    = (float2*)p;     p += (long)2 * 16 * 1024 * 8;    // 0.25 MB
    ushort_t* h     = vT;             // MLP hidden reuses vT
    float*    pgem  = (float*)qk;     // fp32 partials reuse qk (dead post-flash)

    detect_kernel<<<1, 256, 0, stream>>>((const ushort_t*)Wq, 2048, flagp);

    // wqkvT[l] = [3072][256]: rows 0..1023 WqT | 1024..2047 WkT | 2048.. WvT
    tconv_kernel<<<dim3(32, 8, CL), 256, 0, stream>>>(
        Wq, wqkvT, 256, 1024, 256 * 1024, 3072 * 256, 0, flagp);
    tconv_kernel<<<dim3(32, 8, CL), 256, 0, stream>>>(
        Wk, wqkvT + 1024 * 256, 256, 1024, 256 * 1024, 3072 * 256, 0, flagp);
    tconv_kernel<<<dim3(32, 8, CL), 256, 0, stream>>>(
        Wv, wqkvT + 2048 * 256, 256, 1024, 256 * 1024, 3072 * 256, 0, flagp);
    tconv_kernel<<<dim3(32, 8, CL), 256, 0, stream>>>(
        W1, w1T, 256, 1024, 256 * 1024, 1024 * 256, 0, flagp);

    in_convert<<<(NROW * CD) / 1024, 256, 0, stream>>>(queries, xa, flagp);

    for (int l = 0; l < CL; ++l) {
        // 1) merged QKV projection -> qk [4096,2048] + vT[bh][d][t]
        qkv_proj<<<dim3(24, 32, 1), 256, 0, stream>>>(
            xa, wqkvT + (long)l * 3072 * 256, bq, bk, bv, qk, vT,
            (long)l * 1024, flagp);
        // 2) Wo^T -> wscr
        tconv_kernel<<<dim3(8, 32, 1), 256, 0, stream>>>(
            Wo, wscr, 1024, 256, 0, 0, (long)l * 1024 * 256, flagp);
        // 3) flash attention (512 blocks, 32-key tiles, K+V LDS, 2/CU)
        flash_attn<<<512, 256, 0, stream>>>(qk, vT, op0, op1, ml);
        // 4) O projection with fused partial-combine -> fp32 pgem
        mgemm64s<1><<<dim3(4, 64, 2), 256, 0, stream>>>(
            op0, op1, ml, wscr, pgem, 512, 1024, 1024);
        // 5) xa = LN(pgem0+pgem1 + bo + xa)
        ln_p<0><<<NROW, 256, 0, stream>>>(pgem, bo, (long)l * 256, xa,
                                          ln1s, ln1b, xa, (long)l * 256, flagp);
        // 6) h = relu(xa @ w1T^T + b1)  (1024 blocks = 4/CU)
        mgemm64b<1><<<dim3(16, 64, 1), 256, 0, stream>>>(
            xa, w1T + (long)l * 1024 * 256, b1, h,
            256, 256, 256, 1024, (long)l * 1024, flagp);
        // 7) W2^T -> wscr
        tconv_kernel<<<dim3(8, 32, 1), 256, 0, stream>>>(
            W2, wscr, 1024, 256, 0, 0, (long)l * 1024 * 256, flagp);
        // 8) MLP2 -> fp32 pgem
        mgemm64s<0><<<dim3(4, 64, 2), 256, 0, stream>>>(
            h, nullptr, nullptr, wscr, pgem, 512, 1024, 1024);
        // 9) LN(pgem0+pgem1 + b2 + xa): final layer writes d_out directly
        if (l == CL - 1)
            ln_p<1><<<NROW, 256, 0, stream>>>(pgem, b2, (long)l * 256, xa,
                                              ln2s, ln2b, d_out, (long)l * 256, flagp);
        else
            ln_p<0><<<NROW, 256, 0, stream>>>(pgem, b2, (long)l * 256, xa,
                                              ln2s, ln2b, xa, (long)l * 256, flagp);
    }
}

// Round 10
// 316.921 us; speedup vs baseline: 1.6396x; 1.0980x over previous
//
#include <hip/hip_runtime.h>
#include <hip/hip_bf16.h>

#define CL 2
#define CB 4
#define CT 1024
#define CD 256
#define CH 4
#define CM 1024
#define CHD (CH * CD)      // 1024
#define NROW (CB * CT)     // 4096

typedef unsigned short ushort_t;
typedef __attribute__((ext_vector_type(8))) short short8v;   // 8 bf16 (4 VGPR)
typedef __attribute__((ext_vector_type(4))) float float4v;   // MFMA C/D frag

#define LOG2E 1.44269504088896f

__device__ __forceinline__ float bf2f(unsigned short u) {
    return __uint_as_float(((unsigned int)u) << 16);
}
__device__ __forceinline__ unsigned short f2bf(float f) {
    unsigned int x = __float_as_uint(f);
    return (unsigned short)((x + 0x7fffu + ((x >> 16) & 1u)) >> 16);
}

// ---------------------------------------------------------------------------
// Input-dtype detection (2048 elems; fp32-underlying -> ~430 anomalies, bf16 0)
// ---------------------------------------------------------------------------
__global__ __launch_bounds__(256) void detect_kernel(
    const ushort_t* __restrict__ w, int n, int* __restrict__ flag)
{
    __shared__ int red[256];
    int c = 0;
    for (int i = threadIdx.x; i < n; i += 256) {
        float v = bf2f(w[i]);
        if (!(fabsf(v) <= 1e6f)) c++;
    }
    red[threadIdx.x] = c;
    __syncthreads();
    for (int s = 128; s > 0; s >>= 1) {
        if (threadIdx.x < s) red[threadIdx.x] += red[threadIdx.x + s];
        __syncthreads();
    }
    if (threadIdx.x == 0) flag[0] = (red[0] < 8) ? 1 : 0;
}

// ---------------------------------------------------------------------------
// Prepass transpose: Wq/Wk/Wv/W1 (all [L][256][1024]) -> bf16 transposed.
// Grid (32, 8, 8): z = which*2 + l. ONE dispatch replaces four (r9 lesson:
// ~3 us/launch gap across 31 boundaries = ~95 us of the runtime).
// ---------------------------------------------------------------------------
__global__ __launch_bounds__(256) void tconv_all(
    const void* __restrict__ Wq, const void* __restrict__ Wk,
    const void* __restrict__ Wv, const void* __restrict__ W1,
    ushort_t* __restrict__ wqkvT, ushort_t* __restrict__ w1T,
    const int* __restrict__ flagp)
{
    const int fbf = *flagp;
    const int z = blockIdx.z;
    const int which = z >> 1, l = z & 1;
    const void* in = (which == 0) ? Wq : (which == 1) ? Wk
                   : (which == 2) ? Wv : W1;
    ushort_t* out = (which < 3)
        ? wqkvT + (long)l * 3072 * 256 + (long)which * 1024 * 256
        : w1T + (long)l * 1024 * 256;
    const long zi = (long)l * 262144;

    __shared__ float tile[32][33];
    const int r0 = blockIdx.y * 32;         // R = 256
    const int c0 = blockIdx.x * 32;         // C = 1024
    const int tx = threadIdx.x & 31;
    const int ty = threadIdx.x >> 5;
#pragma unroll
    for (int i = 0; i < 32; i += 8) {
        const long idx = zi + (long)(r0 + ty + i) * 1024 + c0 + tx;
        tile[ty + i][tx] = fbf ? bf2f(((const ushort_t*)in)[idx])
                               : ((const float*)in)[idx];
    }
    __syncthreads();
#pragma unroll
    for (int i = 0; i < 32; i += 8)
        out[(long)(c0 + ty + i) * 256 + r0 + tx] = f2bf(tile[tx][ty + i]);
}

// ---------------------------------------------------------------------------
// In-loop transpose: Wo & W2 (both [L][1024][256]) -> wscr[z][256][1024].
// Grid (8, 32, 2): z=0 -> Wo^T, z=1 -> W2^T. One dispatch replaces two.
// ---------------------------------------------------------------------------
__global__ __launch_bounds__(256) void tconv2(
    const void* __restrict__ Wo, const void* __restrict__ W2,
    ushort_t* __restrict__ wscr, long ioff, const int* __restrict__ flagp)
{
    const int fbf = *flagp;
    const int z = blockIdx.z;
    const void* in = z ? W2 : Wo;
    ushort_t* out = wscr + (long)z * 262144;

    __shared__ float tile[32][33];
    const int r0 = blockIdx.y * 32;         // R = 1024
    const int c0 = blockIdx.x * 32;         // C = 256
    const int tx = threadIdx.x & 31;
    const int ty = threadIdx.x >> 5;
#pragma unroll
    for (int i = 0; i < 32; i += 8) {
        const long idx = ioff + (long)(r0 + ty + i) * 256 + c0 + tx;
        tile[ty + i][tx] = fbf ? bf2f(((const ushort_t*)in)[idx])
                               : ((const float*)in)[idx];
    }
    __syncthreads();
#pragma unroll
    for (int i = 0; i < 32; i += 8)
        out[(long)(c0 + ty + i) * 1024 + r0 + tx] = f2bf(tile[tx][ty + i]);
}

// ---------------------------------------------------------------------------
// QKV projection (merged, verified r7-r9): A = xa [4096][256];
// B = wqkvT[l] [3072][256]. 128x128 tiles, grid (24,32)=768 blocks.
// cols<2048 -> qk row-major; cols>=2048 -> V transposed into vT[bh][d][t].
// ---------------------------------------------------------------------------
__global__ __launch_bounds__(256) void qkv_proj(
    const ushort_t* __restrict__ A, const ushort_t* __restrict__ B,
    const void* __restrict__ bq, const void* __restrict__ bk,
    const void* __restrict__ bv, ushort_t* __restrict__ qk,
    ushort_t* __restrict__ vT, long boff, const int* __restrict__ flagp)
{
    const long m0 = (long)blockIdx.y * 128;
    const long n0 = (long)blockIdx.x * 128;

    __shared__ __align__(16) ushort_t As[128 * 32];
    __shared__ __align__(16) ushort_t Bs[128 * 32];

    const int tid = threadIdx.x;
    const int wave = tid >> 6;
    const int lane = tid & 63;
    const int quad = lane >> 4;
    const int lrow = lane & 15;
    const int wm = (wave >> 1) * 64;
    const int wn = (wave & 1) * 64;

    float4v acc[4][4];
#pragma unroll
    for (int i = 0; i < 4; ++i)
#pragma unroll
        for (int j = 0; j < 4; ++j)
            acc[i][j] = (float4v){0.f, 0.f, 0.f, 0.f};

    for (int k0 = 0; k0 < 256; k0 += 32) {
        __syncthreads();
#pragma unroll
        for (int p = 0; p < 2; ++p) {
            const int c = p * 256 + tid;
            const int row = c >> 2;
            const int kk = (c & 3) << 3;
            *reinterpret_cast<short8v*>(&As[c << 3]) =
                *reinterpret_cast<const short8v*>(&A[(m0 + row) * 256 + k0 + kk]);
            *reinterpret_cast<short8v*>(&Bs[c << 3]) =
                *reinterpret_cast<const short8v*>(&B[(n0 + row) * 256 + k0 + kk]);
        }
        __syncthreads();

        short8v af[4], bfv[4];
#pragma unroll
        for (int i = 0; i < 4; ++i) {
            af[i]  = *reinterpret_cast<const short8v*>(&As[(wm + i * 16 + lrow) * 32 + quad * 8]);
            bfv[i] = *reinterpret_cast<const short8v*>(&Bs[(wn + i * 16 + lrow) * 32 + quad * 8]);
        }
#pragma unroll
        for (int mi = 0; mi < 4; ++mi)
#pragma unroll
            for (int ni = 0; ni < 4; ++ni)
                acc[mi][ni] = __builtin_amdgcn_mfma_f32_16x16x32_bf16(
                    af[mi], bfv[ni], acc[mi][ni], 0, 0, 0);
    }

    const int fbf = *flagp;
#pragma unroll
    for (int mi = 0; mi < 4; ++mi) {
#pragma unroll
        for (int ni = 0; ni < 4; ++ni) {
            const long col = n0 + wn + ni * 16 + lrow;
            const long row0 = m0 + wm + mi * 16 + quad * 4;
            const void* bp;
            long bn;
            if (col < 1024)      { bp = bq; bn = col; }
            else if (col < 2048) { bp = bk; bn = col - 1024; }
            else                 { bp = bv; bn = col - 2048; }
            const float bias = fbf ? bf2f(((const ushort_t*)bp)[boff + bn])
                                   : ((const float*)bp)[boff + bn];
            if (col < 2048) {
#pragma unroll
                for (int r = 0; r < 4; ++r)
                    qk[(row0 + r) * 2048 + col] = f2bf(acc[mi][ni][r] + bias);
            } else {
                const long d = col - 2048;
                const long addr = ((row0 >> 10) << 2) * 262144 + d * 1024 + (row0 & 1023);
                ushort4 u;
                u.x = f2bf(acc[mi][ni][0] + bias);
                u.y = f2bf(acc[mi][ni][1] + bias);
                u.z = f2bf(acc[mi][ni][2] + bias);
                u.w = f2bf(acc[mi][ni][3] + bias);
                *reinterpret_cast<ushort4*>(&vT[addr]) = u;
            }
        }
    }
}

// ---------------------------------------------------------------------------
// mgemm64s: 64x64-tile split-K GEMM -> fp32 partials. Grid (N/64, M/64, 2).
// AMODE 0: plain bf16 A. AMODE 1: combined attention partials (exp2 domain).
// ---------------------------------------------------------------------------
template <int AMODE>
__global__ __launch_bounds__(256) void mgemm64s(
    const ushort_t* __restrict__ A, const ushort_t* __restrict__ Ap1,
    const float2* __restrict__ ml, const ushort_t* __restrict__ B,
    float* __restrict__ P, int K2, int lda, int ldb)
{
    const int z = blockIdx.z;
    const long m0 = (long)blockIdx.y * 64;
    const long n0 = (long)blockIdx.x * 64;
    const int k_beg = z * K2;

    __shared__ __align__(16) ushort_t As[64 * 32];
    __shared__ __align__(16) ushort_t Bs[64 * 32];

    const int tid = threadIdx.x;
    const int wave = tid >> 6;
    const int lane = tid & 63;
    const int quad = lane >> 4;
    const int lrow = lane & 15;
    const int wm = (wave >> 1) * 32;
    const int wn = (wave & 1) * 32;

    const int ar = tid >> 2;
    const int ak = (tid & 3) << 3;

    float4v acc[2][2];
#pragma unroll
    for (int i = 0; i < 2; ++i)
#pragma unroll
        for (int j = 0; j < 2; ++j)
            acc[i][j] = (float4v){0.f, 0.f, 0.f, 0.f};

    for (int k0 = k_beg; k0 < k_beg + K2; k0 += 32) {
        __syncthreads();
        if constexpr (AMODE == 0) {
            *reinterpret_cast<short8v*>(&As[tid << 3]) =
                *reinterpret_cast<const short8v*>(&A[(m0 + ar) * (long)lda + k0 + ak]);
        } else {
            const long m = m0 + ar;
            const int hh = (k0 + ak) >> 8;
            const int bh = ((int)(m >> 10) << 2) + hh;
            const int trow = (int)(m & 1023);
            const float2 v0 = ml[bh * 1024 + trow];
            const float2 v1 = ml[(16 + bh) * 1024 + trow];
            const float mm = fmaxf(v0.x, v1.x);
            const float a0 = exp2f(v0.x - mm);
            const float a1 = exp2f(v1.x - mm);
            const float inv = 1.0f / (v0.y * a0 + v1.y * a1);
            const ushort4 u0a = *reinterpret_cast<const ushort4*>(&A[m * 1024 + k0 + ak]);
            const ushort4 u0b = *reinterpret_cast<const ushort4*>(&A[m * 1024 + k0 + ak + 4]);
            const ushort4 u1a = *reinterpret_cast<const ushort4*>(&Ap1[m * 1024 + k0 + ak]);
            const ushort4 u1b = *reinterpret_cast<const ushort4*>(&Ap1[m * 1024 + k0 + ak + 4]);
            short8v t8;
            t8[0] = (short)f2bf((bf2f(u0a.x) * a0 + bf2f(u1a.x) * a1) * inv);
            t8[1] = (short)f2bf((bf2f(u0a.y) * a0 + bf2f(u1a.y) * a1) * inv);
            t8[2] = (short)f2bf((bf2f(u0a.z) * a0 + bf2f(u1a.z) * a1) * inv);
            t8[3] = (short)f2bf((bf2f(u0a.w) * a0 + bf2f(u1a.w) * a1) * inv);
            t8[4] = (short)f2bf((bf2f(u0b.x) * a0 + bf2f(u1b.x) * a1) * inv);
            t8[5] = (short)f2bf((bf2f(u0b.y) * a0 + bf2f(u1b.y) * a1) * inv);
            t8[6] = (short)f2bf((bf2f(u0b.z) * a0 + bf2f(u1b.z) * a1) * inv);
            t8[7] = (short)f2bf((bf2f(u0b.w) * a0 + bf2f(u1b.w) * a1) * inv);
            *reinterpret_cast<short8v*>(&As[tid << 3]) = t8;
        }
        *reinterpret_cast<short8v*>(&Bs[tid << 3]) =
            *reinterpret_cast<const short8v*>(&B[(n0 + ar) * (long)ldb + k0 + ak]);
        __syncthreads();

        short8v af[2], bfv[2];
#pragma unroll
        for (int i = 0; i < 2; ++i) {
            af[i]  = *reinterpret_cast<const short8v*>(&As[(wm + i * 16 + lrow) * 32 + quad * 8]);
            bfv[i] = *reinterpret_cast<const short8v*>(&Bs[(wn + i * 16 + lrow) * 32 + quad * 8]);
        }
#pragma unroll
        for (int mi = 0; mi < 2; ++mi)
#pragma unroll
            for (int ni = 0; ni < 2; ++ni)
                acc[mi][ni] = __builtin_amdgcn_mfma_f32_16x16x32_bf16(
                    af[mi], bfv[ni], acc[mi][ni], 0, 0, 0);
    }

    float* Pz = P + (long)z * NROW * CD;
#pragma unroll
    for (int mi = 0; mi < 2; ++mi)
#pragma unroll
        for (int ni = 0; ni < 2; ++ni) {
            const long col = n0 + wn + ni * 16 + lrow;
            const long row0 = m0 + wm + mi * 16 + quad * 4;
#pragma unroll
            for (int r = 0; r < 4; ++r)
                Pz[(row0 + r) * CD + col] = acc[mi][ni][r];
        }
}

// ---------------------------------------------------------------------------
// mgemm64b: 64x64-tile full-K GEMM, bias(+relu), bf16 out. Grid (N/64, M/64).
// ---------------------------------------------------------------------------
template <int RELU>
__global__ __launch_bounds__(256) void mgemm64b(
    const ushort_t* __restrict__ A, const ushort_t* __restrict__ B,
    const void* __restrict__ bias, ushort_t* __restrict__ C,
    int K, int lda, int ldb, int ldc, long boff,
    const int* __restrict__ flagp)
{
    const long m0 = (long)blockIdx.y * 64;
    const long n0 = (long)blockIdx.x * 64;

    __shared__ __align__(16) ushort_t As[64 * 32];
    __shared__ __align__(16) ushort_t Bs[64 * 32];

    const int tid = threadIdx.x;
    const int wave = tid >> 6;
    const int lane = tid & 63;
    const int quad = lane >> 4;
    const int lrow = lane & 15;
    const int wm = (wave >> 1) * 32;
    const int wn = (wave & 1) * 32;

    const int ar = tid >> 2;
    const int ak = (tid & 3) << 3;

    float4v acc[2][2];
#pragma unroll
    for (int i = 0; i < 2; ++i)
#pragma unroll
        for (int j = 0; j < 2; ++j)
            acc[i][j] = (float4v){0.f, 0.f, 0.f, 0.f};

    for (int k0 = 0; k0 < K; k0 += 32) {
        __syncthreads();
        *reinterpret_cast<short8v*>(&As[tid << 3]) =
            *reinterpret_cast<const short8v*>(&A[(m0 + ar) * (long)lda + k0 + ak]);
        *reinterpret_cast<short8v*>(&Bs[tid << 3]) =
            *reinterpret_cast<const short8v*>(&B[(n0 + ar) * (long)ldb + k0 + ak]);
        __syncthreads();

        short8v af[2], bfv[2];
#pragma unroll
        for (int i = 0; i < 2; ++i) {
            af[i]  = *reinterpret_cast<const short8v*>(&As[(wm + i * 16 + lrow) * 32 + quad * 8]);
            bfv[i] = *reinterpret_cast<const short8v*>(&Bs[(wn + i * 16 + lrow) * 32 + quad * 8]);
        }
#pragma unroll
        for (int mi = 0; mi < 2; ++mi)
#pragma unroll
            for (int ni = 0; ni < 2; ++ni)
                acc[mi][ni] = __builtin_amdgcn_mfma_f32_16x16x32_bf16(
                    af[mi], bfv[ni], acc[mi][ni], 0, 0, 0);
    }

    const int fbf = *flagp;
#pragma unroll
    for (int mi = 0; mi < 2; ++mi)
#pragma unroll
        for (int ni = 0; ni < 2; ++ni) {
            const long col = n0 + wn + ni * 16 + lrow;
            const long row0 = m0 + wm + mi * 16 + quad * 4;
            const float bv = fbf ? bf2f(((const ushort_t*)bias)[boff + col])
                                 : ((const float*)bias)[boff + col];
#pragma unroll
            for (int r = 0; r < 4; ++r) {
                float v = acc[mi][ni][r] + bv;
                if (RELU) v = fmaxf(v, 0.f);
                C[(row0 + r) * (long)ldc + col] = f2bf(v);
            }
        }
}

// ---------------------------------------------------------------------------
// Flash attention v5 = r9's proven structure (32-key tiles, K+V LDS 42.5 KB,
// 2 blocks/CU) with S^T softmax: QK MFMA operand order SWAPPED ->
// S^T[key][qrow] (col = q-row = lane&15). Each lane then owns ONE q-row's
// 8 key-values: max/sum = in-lane reg reduction + 2 shfl steps (xor 16,32)
// vs the old 4-step x 4-row chains. Per iter: 32->8 shfls, 12->9 exps;
// m/l are per-lane scalars (q-row = lrow, duplicated across quads).
// PV unchanged (Ps now [qrow][key]; A-frag read is 16B-aligned).
// ---------------------------------------------------------------------------
__global__ __launch_bounds__(256) void flash_attn(
    const ushort_t* __restrict__ qk, const ushort_t* __restrict__ vT,
    ushort_t* __restrict__ op0, ushort_t* __restrict__ op1,
    float2* __restrict__ ml)
{
    const int bx = blockIdx.x;
    const int bh = bx & 15;
    const int qt = (bx >> 4) & 15;
    const int ck = bx >> 8;
    const int b = bh >> 2, h = bh & 3;

    __shared__ __align__(16) ushort_t Ks[32 * 264];     // 16896 B
    __shared__ __align__(16) ushort_t Vs[256 * 40];     // 20480 B
    __shared__ __align__(16) ushort_t Ps[4][16 * 40];   //  5120 B

    const int tid = threadIdx.x;
    const int wave = tid >> 6;
    const int lane = tid & 63;
    const int quad = lane >> 4;
    const int lrow = lane & 15;

    const long qrow0 = (long)b * CT + qt * 64;
    const int qcol = h * 256;
    const int kcol = 1024 + h * 256;
    const long vbase = (long)bh * 256 * 1024;
    const float SC = 0.0625f * LOG2E;

    short8v qf[8];
#pragma unroll
    for (int kk = 0; kk < 8; ++kk)
        qf[kk] = *reinterpret_cast<const short8v*>(
            &qk[(qrow0 + wave * 16 + lrow) * 2048 + qcol + kk * 32 + quad * 8]);

    // per-lane online-softmax state for q-row = lrow (dup across quads)
    float mrun = -1e30f, lrun = 0.f;
    float4v oacc[16];
#pragma unroll
    for (int i = 0; i < 16; ++i) oacc[i] = (float4v){0.f, 0.f, 0.f, 0.f};

    const int t_beg = ck * 512;
    for (int t0 = t_beg; t0 < t_beg + 512; t0 += 32) {
        __syncthreads();
        // stage K 32x256 and V 256x32 (1024 16B-chunks each, 4/thread each)
#pragma unroll
        for (int p = 0; p < 4; ++p) {
            const int c = p * 256 + tid;
            {
                const int r = c >> 5, col = (c & 31) * 8;
                *reinterpret_cast<short8v*>(&Ks[r * 264 + col]) =
                    *reinterpret_cast<const short8v*>(
                        &qk[((long)b * CT + t0 + r) * 2048 + kcol + col]);
            }
            {
                const int r = c >> 2, col = (c & 3) * 8;
                *reinterpret_cast<short8v*>(&Vs[r * 40 + col]) =
                    *reinterpret_cast<const short8v*>(
                        &vT[vbase + (long)r * 1024 + t0 + col]);
            }
        }
        __syncthreads();

        // S^T strip: 32 keys x 16 q-rows, wave-private. A = K-frag, B = Q.
        float4v sacc[2];
        sacc[0] = (float4v){0.f, 0.f, 0.f, 0.f};
        sacc[1] = (float4v){0.f, 0.f, 0.f, 0.f};
#pragma unroll
        for (int kk = 0; kk < 8; ++kk) {
#pragma unroll
            for (int ni = 0; ni < 2; ++ni) {
                short8v bk = *reinterpret_cast<const short8v*>(
                    &Ks[(ni * 16 + lrow) * 264 + kk * 32 + quad * 8]);
                sacc[ni] = __builtin_amdgcn_mfma_f32_16x16x32_bf16(
                    bk, qf[kk], sacc[ni], 0, 0, 0);   // SWAPPED -> S^T
            }
        }
#pragma unroll
        for (int ni = 0; ni < 2; ++ni)
#pragma unroll
            for (int r = 0; r < 4; ++r)
                sacc[ni][r] *= SC;

        // online softmax (log2 domain), per-lane q-row = lrow:
        float mx = fmaxf(fmaxf(fmaxf(sacc[0][0], sacc[0][1]),
                               fmaxf(sacc[0][2], sacc[0][3])),
                         fmaxf(fmaxf(sacc[1][0], sacc[1][1]),
                               fmaxf(sacc[1][2], sacc[1][3])));
        mx = fmaxf(mx, __shfl_xor(mx, 16));
        mx = fmaxf(mx, __shfl_xor(mx, 32));
        const float mnew = fmaxf(mrun, mx);
        const float alpha = exp2f(mrun - mnew);
        mrun = mnew;

        float s = 0.f;
#pragma unroll
        for (int ni = 0; ni < 2; ++ni)
#pragma unroll
            for (int r = 0; r < 4; ++r) {
                const float pv = exp2f(sacc[ni][r] - mnew);
                s += pv;
                // P^T[key][qrow] -> Ps[qrow][key]
                Ps[wave][lrow * 40 + ni * 16 + quad * 4 + r] = f2bf(pv);
            }
        s += __shfl_xor(s, 16);
        s += __shfl_xor(s, 32);
        lrun = lrun * alpha + s;

        // rescale oacc rows (quad*4+r) by alpha of q-row quad*4+r; skip when
        // no row's max moved (wave-uniform branch)
        if (__ballot(alpha < 1.0f) != 0ull) {
            float a4[4];
#pragma unroll
            for (int r = 0; r < 4; ++r)
                a4[r] = __shfl(alpha, quad * 4 + r);
#pragma unroll
            for (int ni = 0; ni < 16; ++ni)
#pragma unroll
                for (int r = 0; r < 4; ++r)
                    oacc[ni][r] *= a4[r];
        }

        // O += P(16x32) @ V(32x256): A = Ps[qrow][key] (16B-aligned), B = Vs
        {
            short8v ap = *reinterpret_cast<const short8v*>(
                &Ps[wave][lrow * 40 + quad * 8]);
#pragma unroll
            for (int ni = 0; ni < 16; ++ni) {
                short8v bv = *reinterpret_cast<const short8v*>(
                    &Vs[(ni * 16 + lrow) * 40 + quad * 8]);
                oacc[ni] = __builtin_amdgcn_mfma_f32_16x16x32_bf16(
                    ap, bv, oacc[ni], 0, 0, 0);
            }
        }
    }

    // epilogue: (m,l) per q-row (log2-units), one quad writes
    if (quad == 0)
        ml[((ck << 4) + bh) * 1024 + qt * 64 + wave * 16 + lrow] =
            make_float2(mrun, lrun);

    ushort_t* op = ck ? op1 : op0;
#pragma unroll
    for (int ni = 0; ni < 16; ++ni)
#pragma unroll
        for (int r = 0; r < 4; ++r)
            op[(qrow0 + wave * 16 + quad * 4 + r) * 1024 + (h << 8) + ni * 16 + lrow]
                = f2bf(oacc[ni][r]);
}

// ---------------------------------------------------------------------------
// ln_p: x = P0[row]+P1[row] + gbias + res; y = LN(x)*s + b.
// FINAL=1 writes d_out in flag dtype.
// ---------------------------------------------------------------------------
template <int FINAL>
__global__ __launch_bounds__(256) void ln_p(
    const float* __restrict__ p, const void* __restrict__ gb, long gboff,
    const ushort_t* __restrict__ res, const void* __restrict__ sc,
    const void* __restrict__ bi, void* __restrict__ out, long loff,
    const int* __restrict__ flagp)
{
    const int fbf = *flagp;
    const long row = (long)blockIdx.x * CD;
    const int t = threadIdx.x;
    const float gbv = fbf ? bf2f(((const ushort_t*)gb)[gboff + t])
                          : ((const float*)gb)[gboff + t];
    const float x = p[row + t] + p[(long)NROW * CD + row + t] + gbv + bf2f(res[row + t]);

    __shared__ float r1[256];
    __shared__ float r2[256];
    r1[t] = x;
    r2[t] = x * x;
    __syncthreads();
    for (int s = 128; s > 0; s >>= 1) {
        if (t < s) { r1[t] += r1[t + s]; r2[t] += r2[t + s]; }
        __syncthreads();
    }
    const float mean = r1[0] * (1.0f / CD);
    const float var = r2[0] * (1.0f / CD) - mean * mean;
    const float rstd = rsqrtf(var + 1e-5f);
    const float s_v = fbf ? bf2f(((const ushort_t*)sc)[loff + t]) : ((const float*)sc)[loff + t];
    const float b_v = fbf ? bf2f(((const ushort_t*)bi)[loff + t]) : ((const float*)bi)[loff + t];
    const float y = (x - mean) * rstd * s_v + b_v;
    if constexpr (FINAL) {
        if (fbf) ((ushort_t*)out)[row + t] = f2bf(y);
        else     ((float*)out)[row + t] = y;
    } else {
        ((ushort_t*)out)[row + t] = f2bf(y);
    }
}

__global__ __launch_bounds__(256) void in_convert(
    const void* __restrict__ in, ushort_t* __restrict__ x,
    const int* __restrict__ flagp)
{
    const int fbf = *flagp;
    const long i = ((long)blockIdx.x * 256 + threadIdx.x) << 2;
    if (fbf) {
        *reinterpret_cast<ushort4*>(x + i) =
            *reinterpret_cast<const ushort4*>((const ushort_t*)in + i);
    } else {
        float4 f = *reinterpret_cast<const float4*>((const float*)in + i);
        ushort4 u;
        u.x = f2bf(f.x); u.y = f2bf(f.y); u.z = f2bf(f.z); u.w = f2bf(f.w);
        *reinterpret_cast<ushort4*>(x + i) = u;
    }
}

// ---------------------------------------------------------------------------
// Orchestration. ws = 47.25 MB + 256 B (< 48 MB + 256 known-safe).
// Dispatches: 3 prepass + 8/layer x 2 = 19 (r9: 25).
// ---------------------------------------------------------------------------
extern "C" void kernel_launch(void* const* d_in, const int* in_sizes, int n_in,
                              void* d_out, int out_size, void* d_ws, size_t ws_size,
                              hipStream_t stream)
{
    const void* queries = d_in[0];
    const void* Wq = d_in[1];  const void* bq = d_in[2];
    const void* Wk = d_in[3];  const void* bk = d_in[4];
    const void* Wv = d_in[5];  const void* bv = d_in[6];
    const void* Wo = d_in[7];  const void* bo = d_in[8];
    const void* ln1s = d_in[9];  const void* ln1b = d_in[10];
    const void* W1 = d_in[11]; const void* b1 = d_in[12];
    const void* W2 = d_in[13]; const void* b2 = d_in[14];
    const void* ln2s = d_in[15]; const void* ln2b = d_in[16];

    char* p = (char*)d_ws;
    int* flagp = (int*)p;             p += 256;
    ushort_t* wqkvT = (ushort_t*)p;   p += (long)CL * 3072 * 256 * 2;  // 3 MB
    ushort_t* w1T   = (ushort_t*)p;   p += (long)CL * 1024 * 256 * 2;  // 1 MB
    ushort_t* wscr  = (ushort_t*)p;   p += (long)2 * 256 * 1024 * 2;   // 1 MB
    ushort_t* xa    = (ushort_t*)p;   p += (long)NROW * CD * 2;        // 2 MB
    ushort_t* qk    = (ushort_t*)p;   p += (long)NROW * 2048 * 2;      // 16 MB
    ushort_t* vT    = (ushort_t*)p;   p += (long)16 * 256 * 1024 * 2;  // 8 MB
    ushort_t* op0   = (ushort_t*)p;   p += (long)NROW * 1024 * 2;      // 8 MB
    ushort_t* op1   = (ushort_t*)p;   p += (long)NROW * 1024 * 2;      // 8 MB
    float2*   ml    = (float2*)p;     p += (long)2 * 16 * 1024 * 8;    // 0.25 MB
    ushort_t* h     = vT;             // MLP hidden reuses vT
    float*    pgem  = (float*)qk;     // fp32 partials reuse qk (dead post-flash)

    detect_kernel<<<1, 256, 0, stream>>>((const ushort_t*)Wq, 2048, flagp);

    // all [256][1024]->T transposes in ONE dispatch (Wq/Wk/Wv/W1 x 2 layers)
    tconv_all<<<dim3(32, 8, 8), 256, 0, stream>>>(
        Wq, Wk, Wv, W1, wqkvT, w1T, flagp);

    in_convert<<<(NROW * CD) / 1024, 256, 0, stream>>>(queries, xa, flagp);

    for (int l = 0; l < CL; ++l) {
        // 1) merged QKV projection -> qk [4096,2048] + vT[bh][d][t]
        qkv_proj<<<dim3(24, 32, 1), 256, 0, stream>>>(
            xa, wqkvT + (long)l * 3072 * 256, bq, bk, bv, qk, vT,
            (long)l * 1024, flagp);
        // 2) Wo^T and W2^T in one dispatch -> wscr[0], wscr[1]
        tconv2<<<dim3(8, 32, 2), 256, 0, stream>>>(
            Wo, W2, wscr, (long)l * 1024 * 256, flagp);
        // 3) flash attention (512 blocks, 32-key tiles, S^T softmax)
        flash_attn<<<512, 256, 0, stream>>>(qk, vT, op0, op1, ml);
        // 4) O projection with fused partial-combine -> fp32 pgem
        mgemm64s<1><<<dim3(4, 64, 2), 256, 0, stream>>>(
            op0, op1, ml, wscr, pgem, 512, 1024, 1024);
        // 5) xa = LN(pgem0+pgem1 + bo + xa)
        ln_p<0><<<NROW, 256, 0, stream>>>(pgem, bo, (long)l * 256, xa,
                                          ln1s, ln1b, xa, (long)l * 256, flagp);
        // 6) h = relu(xa @ w1T^T + b1)  (1024 blocks = 4/CU)
        mgemm64b<1><<<dim3(16, 64, 1), 256, 0, stream>>>(
            xa, w1T + (long)l * 1024 * 256, b1, h,
            256, 256, 256, 1024, (long)l * 1024, flagp);
        // 7) MLP2 -> fp32 pgem  (B = W2^T in wscr[1])
        mgemm64s<0><<<dim3(4, 64, 2), 256, 0, stream>>>(
            h, nullptr, nullptr, wscr + 262144, pgem, 512, 1024, 1024);
        // 8) LN(pgem0+pgem1 + b2 + xa): final layer writes d_out directly
        if (l == CL - 1)
            ln_p<1><<<NROW, 256, 0, stream>>>(pgem, b2, (long)l * 256, xa,
                                              ln2s, ln2b, d_out, (long)l * 256, flagp);
        else
            ln_p<0><<<NROW, 256, 0, stream>>>(pgem, b2, (long)l * 256, xa,
                                              ln2s, ln2b, xa, (long)l * 256, flagp);
    }
}